// Round 4
// baseline (350.335 us; speedup 1.0000x reference)
//
#include <hip/hip_runtime.h>
#include <cstdint>
#include <cstddef>

#define AS1 __attribute__((address_space(1)))
#define AS3 __attribute__((address_space(3)))

typedef __bf16 bf16x8 __attribute__((ext_vector_type(8)));
typedef __bf16 bf16x4 __attribute__((ext_vector_type(4)));
typedef float  f32x4  __attribute__((ext_vector_type(4)));

#define MFMA_BF16(a, b, c) __builtin_amdgcn_mfma_f32_16x16x32_bf16((a), (b), (c), 0, 0, 0)

// async global->LDS, 16B/lane. LDS base wave-uniform; HW adds lane*16.
__device__ __forceinline__ void gload16(const __bf16* g, __bf16* l) {
  __builtin_amdgcn_global_load_lds((AS1 void*)(uintptr_t)g, (AS3 void*)l, 16, 0, 0);
}

// ---------------- fp32 -> bf16 conversion (8 elems/thread) ----------------
__global__ void cvt_kernel(const float* __restrict__ s, __bf16* __restrict__ d, int n8) {
  int i = blockIdx.x * blockDim.x + threadIdx.x;
  const int stride = gridDim.x * blockDim.x;
  for (; i < n8; i += stride) {
    const float4* p = (const float4*)(s + (size_t)i * 8);
    float4 a = p[0], b = p[1];
    bf16x8 v;
    v[0] = (__bf16)a.x; v[1] = (__bf16)a.y; v[2] = (__bf16)a.z; v[3] = (__bf16)a.w;
    v[4] = (__bf16)b.x; v[5] = (__bf16)b.y; v[6] = (__bf16)b.z; v[7] = (__bf16)b.w;
    *(bf16x8*)(d + (size_t)i * 8) = v;
  }
}

// ---------------- mask all-zero? (mask is fp32) ----------------
__global__ void maskflag_kernel(const unsigned long long* __restrict__ m, int* __restrict__ flag) {
  const int n64 = 2048 * 2048 * 4 / 8;
  int idx = blockIdx.x * blockDim.x + threadIdx.x;
  bool nz = false;
  for (int i = idx; i < n64; i += gridDim.x * blockDim.x) nz |= (m[i] != 0ull);
  if (nz) atomicOr(flag, 1);
}

// ---------------- fused QGKV projection (bf16 in, bf16 out, fp32 acc) ----------------
__global__ __launch_bounds__(256) void proj_kernel(
    const __bf16* __restrict__ X,
    const __bf16* __restrict__ qw, const float* __restrict__ qb,
    const __bf16* __restrict__ kw, const float* __restrict__ kb,
    const __bf16* __restrict__ vw, const float* __restrict__ vb,
    __bf16* __restrict__ Qo, __bf16* __restrict__ Ko,
    __bf16* __restrict__ VTo, __bf16* __restrict__ Go)
{
  __shared__ __bf16 As[128][64];
  __shared__ __bf16 Bs[128][64];

  const int bid = blockIdx.x;
  const int r = bid >> 3;
  const int ntile = (bid & 7) * 4 + (r >> 5);
  const int mtile = r & 31;
  const int m0 = mtile * 128;
  const int n0 = ntile * 128;

  const __bf16* W; const float* bias; int nb;
  if (n0 < 2048)      { W = qw; bias = qb; nb = n0; }
  else if (n0 < 3072) { W = kw; bias = kb; nb = n0 - 2048; }
  else                { W = vw; bias = vb; nb = n0 - 3072; }

  const int tid = threadIdx.x;
  const int wv = tid >> 6, ln = tid & 63;
  const int wr = wv >> 1, wc = wv & 1;
  const int qr = ln & 15, qg = ln >> 4;
  const int lrow = ln >> 3, lcol = (ln & 7) * 8;

  f32x4 acc[4][4];
#pragma unroll
  for (int m = 0; m < 4; ++m)
#pragma unroll
    for (int n = 0; n < 4; ++n) acc[m][n] = 0.f;

  for (int k0 = 0; k0 < 1024; k0 += 64) {
    // async global->LDS staging (16B/lane), wave-uniform LDS base
#pragma unroll
    for (int i = 0; i < 4; ++i) {
      const int rb = i * 32 + wv * 8;
      gload16(X + (size_t)(m0 + rb + lrow) * 1024 + k0 + lcol, &As[rb][0]);
      gload16(W + (size_t)(nb + rb + lrow) * 1024 + k0 + lcol, &Bs[rb][0]);
    }
    __syncthreads();
#pragma unroll
    for (int kk = 0; kk < 2; ++kk) {
      bf16x8 af[4], bfv[4];
#pragma unroll
      for (int m = 0; m < 4; ++m) af[m] = *(const bf16x8*)&As[wr * 64 + m * 16 + qr][kk * 32 + qg * 8];
#pragma unroll
      for (int n = 0; n < 4; ++n) bfv[n] = *(const bf16x8*)&Bs[wc * 64 + n * 16 + qr][kk * 32 + qg * 8];
#pragma unroll
      for (int m = 0; m < 4; ++m)
#pragma unroll
        for (int n = 0; n < 4; ++n) acc[m][n] = MFMA_BF16(af[m], bfv[n], acc[m][n]);
    }
    __syncthreads();
  }

  // epilogue: C/D layout col=lane&15, row=(lane>>4)*4+reg
#pragma unroll
  for (int m = 0; m < 4; ++m) {
    const int gm0 = m0 + wr * 64 + m * 16 + qg * 4;
    const int b = gm0 >> 11;
    const int s = gm0 & 2047;
#pragma unroll
    for (int n = 0; n < 4; ++n) {
      const int nl = wc * 64 + n * 16 + qr;
      const float bb = bias[nb + nl];
      if (n0 < 1024) {            // Q -> [b,h,s,d]
        const int col = n0 + nl, hh = col >> 6, dd = col & 63;
        __bf16* dst = Qo + ((size_t)((b << 4) + hh)) * 131072 + (size_t)s * 64 + dd;
#pragma unroll
        for (int rr = 0; rr < 4; ++rr) dst[(size_t)rr * 64] = (__bf16)(acc[m][n][rr] + bb);
      } else if (n0 < 2048) {     // gate -> sigmoid -> [token, h*64+d]
        const int j = n0 - 1024 + nl;
        __bf16* dst = Go + (size_t)gm0 * 1024 + j;
#pragma unroll
        for (int rr = 0; rr < 4; ++rr) {
          const float v = acc[m][n][rr] + bb;
          dst[(size_t)rr * 1024] = (__bf16)(1.f / (1.f + __expf(-v)));
        }
      } else if (n0 < 3072) {     // K -> [b,h,s,d]
        const int j = n0 - 2048 + nl, hh = j >> 6, dd = j & 63;
        __bf16* dst = Ko + ((size_t)((b << 4) + hh)) * 131072 + (size_t)s * 64 + dd;
#pragma unroll
        for (int rr = 0; rr < 4; ++rr) dst[(size_t)rr * 64] = (__bf16)(acc[m][n][rr] + bb);
      } else {                    // V -> transposed [b,h,d,s]
        const int j = n0 - 3072 + nl, hh = j >> 6, dd = j & 63;
        bf16x4 pv;
#pragma unroll
        for (int rr = 0; rr < 4; ++rr) pv[rr] = (__bf16)(acc[m][n][rr] + bb);
        *(bf16x4*)(VTo + ((size_t)((b << 4) + hh)) * 131072 + (size_t)dd * 2048 + s) = pv;
      }
    }
  }
}

// ---------------- flash attention, 1 wave / 16 q-rows (QBLK=16 for occupancy) ----------------
__global__ __launch_bounds__(64, 4) void attn_kernel(
    const __bf16* __restrict__ Qb, const __bf16* __restrict__ Kb,
    const __bf16* __restrict__ VT, const __bf16* __restrict__ G,
    const float* __restrict__ mask, const int* __restrict__ flag,
    __bf16* __restrict__ attn)
{
  __shared__ __bf16 Pt[16][72];
  const int bid = blockIdx.x;    // 4096 = 32 heads * 128 q-tiles
  const int y = bid >> 3;        // 0..511
  const int hl = (bid & 7) * 4 + (y >> 7);  // head-linear 0..31; 4 heads per XCD
  const int qt = y & 127;
  const int q0 = qt * 16;
  const int ln = threadIdx.x;
  const int qr = ln & 15, qg = ln >> 4;
  const int b = hl >> 4, h = hl & 15;

  const __bf16* Qh = Qb + (size_t)hl * 131072;
  const __bf16* Kh = Kb + (size_t)hl * 131072;
  const __bf16* Vh = VT + (size_t)hl * 131072;

  bf16x8 qf[2];
#pragma unroll
  for (int kk = 0; kk < 2; ++kk)
    qf[kk] = *(const bf16x8*)(Qh + (size_t)(q0 + qr) * 64 + kk * 32 + qg * 8);

  f32x4 o[4];
  float mrun[4], lrun[4];
#pragma unroll
  for (int df = 0; df < 4; ++df) o[df] = 0.f;
#pragma unroll
  for (int rr = 0; rr < 4; ++rr) { mrun[rr] = -1e30f; lrun[rr] = 0.f; }

  const bool um = (*flag) != 0;

  for (int kv0 = 0; kv0 < 2048; kv0 += 64) {
    bf16x8 kf[4][2];
#pragma unroll
    for (int n = 0; n < 4; ++n)
#pragma unroll
      for (int kk = 0; kk < 2; ++kk)
        kf[n][kk] = *(const bf16x8*)(Kh + (size_t)(kv0 + n * 16 + qr) * 64 + kk * 32 + qg * 8);

    f32x4 sacc[4];
#pragma unroll
    for (int n = 0; n < 4; ++n) {
      sacc[n] = 0.f;
      sacc[n] = MFMA_BF16(qf[0], kf[n][0], sacc[n]);
      sacc[n] = MFMA_BF16(qf[1], kf[n][1], sacc[n]);
    }

    float sv[4][4];
#pragma unroll
    for (int n = 0; n < 4; ++n)
#pragma unroll
      for (int rr = 0; rr < 4; ++rr) sv[n][rr] = sacc[n][rr] * 0.125f;

    if (um) {
#pragma unroll
      for (int rr = 0; rr < 4; ++rr) {
        const int row = q0 + qg * 4 + rr;
#pragma unroll
        for (int n = 0; n < 4; ++n)
          sv[n][rr] += mask[(size_t)row * 2048 + kv0 + n * 16 + qr];
      }
    }

    float alpha[4];
#pragma unroll
    for (int rr = 0; rr < 4; ++rr) {
      float t = fmaxf(fmaxf(sv[0][rr], sv[1][rr]), fmaxf(sv[2][rr], sv[3][rr]));
      t = fmaxf(t, __shfl_xor(t, 1));
      t = fmaxf(t, __shfl_xor(t, 2));
      t = fmaxf(t, __shfl_xor(t, 4));
      t = fmaxf(t, __shfl_xor(t, 8));
      const float mn = fmaxf(mrun[rr], t);
      const float al = __expf(mrun[rr] - mn);
      mrun[rr] = mn;
      float ps = 0.f;
#pragma unroll
      for (int n = 0; n < 4; ++n) {
        const float p = __expf(sv[n][rr] - mn);
        sv[n][rr] = p;
        ps += p;
      }
      ps += __shfl_xor(ps, 1);
      ps += __shfl_xor(ps, 2);
      ps += __shfl_xor(ps, 4);
      ps += __shfl_xor(ps, 8);
      lrun[rr] = lrun[rr] * al + ps;
      alpha[rr] = al;
    }
#pragma unroll
    for (int df = 0; df < 4; ++df)
#pragma unroll
      for (int rr = 0; rr < 4; ++rr) o[df][rr] *= alpha[rr];

    __syncthreads();  // WAR
#pragma unroll
    for (int n = 0; n < 4; ++n)
#pragma unroll
      for (int rr = 0; rr < 4; ++rr)
        Pt[qg * 4 + rr][n * 16 + qr] = (__bf16)sv[n][rr];
    __syncthreads();  // RAW

#pragma unroll
    for (int kc = 0; kc < 2; ++kc) {
      bf16x8 pf, vf[4];
      pf = *(const bf16x8*)&Pt[qr][kc * 32 + qg * 8];
#pragma unroll
      for (int df = 0; df < 4; ++df)
        vf[df] = *(const bf16x8*)(Vh + (size_t)(df * 16 + qr) * 2048 + kv0 + kc * 32 + qg * 8);
#pragma unroll
      for (int df = 0; df < 4; ++df) o[df] = MFMA_BF16(pf, vf[df], o[df]);
    }
  }

  // epilogue: 1/l, gate, store attn in [b, s, h*64+d]
#pragma unroll
  for (int rr = 0; rr < 4; ++rr) {
    const float inv = 1.f / lrun[rr];
    const int row = q0 + qg * 4 + rr;
    const size_t base = ((size_t)(b * 2048 + row)) * 1024 + h * 64;
#pragma unroll
    for (int df = 0; df < 4; ++df) {
      const int d = df * 16 + qr;
      const float g = (float)G[base + d];
      attn[base + d] = (__bf16)(o[df][rr] * inv * g);
    }
  }
}

// ---------------- O projection (bf16 in, fp32 out) ----------------
__global__ __launch_bounds__(256) void oproj_kernel(
    const __bf16* __restrict__ A, const __bf16* __restrict__ ow,
    const float* __restrict__ ob, float* __restrict__ C)
{
  __shared__ __bf16 As[128][64];
  __shared__ __bf16 Bs[128][64];
  const int bid = blockIdx.x;
  const int ntile = bid & 7;
  const int mtile = bid >> 3;
  const int m0 = mtile * 128, n0 = ntile * 128;

  const int tid = threadIdx.x;
  const int wv = tid >> 6, ln = tid & 63;
  const int wr = wv >> 1, wc = wv & 1;
  const int qr = ln & 15, qg = ln >> 4;
  const int lrow = ln >> 3, lcol = (ln & 7) * 8;

  f32x4 acc[4][4];
#pragma unroll
  for (int m = 0; m < 4; ++m)
#pragma unroll
    for (int n = 0; n < 4; ++n) acc[m][n] = 0.f;

  for (int k0 = 0; k0 < 1024; k0 += 64) {
#pragma unroll
    for (int i = 0; i < 4; ++i) {
      const int rb = i * 32 + wv * 8;
      gload16(A + (size_t)(m0 + rb + lrow) * 1024 + k0 + lcol, &As[rb][0]);
      gload16(ow + (size_t)(n0 + rb + lrow) * 1024 + k0 + lcol, &Bs[rb][0]);
    }
    __syncthreads();
#pragma unroll
    for (int kk = 0; kk < 2; ++kk) {
      bf16x8 af[4], bfv[4];
#pragma unroll
      for (int m = 0; m < 4; ++m) af[m] = *(const bf16x8*)&As[wr * 64 + m * 16 + qr][kk * 32 + qg * 8];
#pragma unroll
      for (int n = 0; n < 4; ++n) bfv[n] = *(const bf16x8*)&Bs[wc * 64 + n * 16 + qr][kk * 32 + qg * 8];
#pragma unroll
      for (int m = 0; m < 4; ++m)
#pragma unroll
        for (int n = 0; n < 4; ++n) acc[m][n] = MFMA_BF16(af[m], bfv[n], acc[m][n]);
    }
    __syncthreads();
  }

#pragma unroll
  for (int m = 0; m < 4; ++m) {
    const int gm0 = m0 + wr * 64 + m * 16 + qg * 4;
#pragma unroll
    for (int n = 0; n < 4; ++n) {
      const int gn = n0 + wc * 64 + n * 16 + qr;
      const float bb = ob[gn];
      float* dst = C + (size_t)gm0 * 1024 + gn;
#pragma unroll
      for (int rr = 0; rr < 4; ++rr) dst[(size_t)rr * 1024] = acc[m][n][rr] + bb;
    }
  }
}

extern "C" void kernel_launch(void* const* d_in, const int* in_sizes, int n_in,
                              void* d_out, int out_size, void* d_ws, size_t ws_size,
                              hipStream_t stream)
{
  const float* hs   = (const float*)d_in[0];
  const float* mask = (const float*)d_in[1];
  const float* qw   = (const float*)d_in[2];
  const float* qb   = (const float*)d_in[3];
  const float* kw   = (const float*)d_in[4];
  const float* kb   = (const float*)d_in[5];
  const float* vw   = (const float*)d_in[6];
  const float* vb   = (const float*)d_in[7];
  const float* ow   = (const float*)d_in[8];
  const float* ob   = (const float*)d_in[9];
  float* out = (float*)d_out;

  char* w = (char*)d_ws;
  int*    flag = (int*)w;
  __bf16* Xb  = (__bf16*)(w + 256);
  __bf16* qwb = Xb  + 4194304;
  __bf16* kwb = qwb + 2097152;
  __bf16* vwb = kwb + 1048576;
  __bf16* owb = vwb + 1048576;
  __bf16* Qo  = owb + 1048576;
  __bf16* Ko  = Qo  + 4194304;
  __bf16* VTo = Ko  + 4194304;
  __bf16* Go  = VTo + 4194304;
  __bf16* At  = Go  + 4194304;

  hipMemsetAsync(flag, 0, sizeof(int), stream);
  cvt_kernel<<<1024, 256, 0, stream>>>(hs, Xb,  4194304 / 8);
  cvt_kernel<<<512,  256, 0, stream>>>(qw, qwb, 2097152 / 8);
  cvt_kernel<<<512,  256, 0, stream>>>(kw, kwb, 1048576 / 8);
  cvt_kernel<<<512,  256, 0, stream>>>(vw, vwb, 1048576 / 8);
  cvt_kernel<<<512,  256, 0, stream>>>(ow, owb, 1048576 / 8);
  maskflag_kernel<<<512, 256, 0, stream>>>((const unsigned long long*)mask, flag);
  proj_kernel<<<1024, 256, 0, stream>>>(Xb, qwb, qb, kwb, kb, vwb, vb, Qo, Ko, VTo, Go);
  attn_kernel<<<4096, 64, 0, stream>>>(Qo, Ko, VTo, Go, mask, flag, At);
  oproj_kernel<<<256, 256, 0, stream>>>(At, owb, ob, out);
}

// Round 5
// 237.776 us; speedup vs baseline: 1.4734x; 1.4734x over previous
//
#include <hip/hip_runtime.h>
#include <cstdint>
#include <cstddef>

#define AS1 __attribute__((address_space(1)))
#define AS3 __attribute__((address_space(3)))

typedef __bf16 bf16x8 __attribute__((ext_vector_type(8)));
typedef __bf16 bf16x4 __attribute__((ext_vector_type(4)));
typedef float  f32x4  __attribute__((ext_vector_type(4)));
typedef float  f32x16 __attribute__((ext_vector_type(16)));
typedef unsigned int u32x4 __attribute__((ext_vector_type(4)));

#define MFMA_BF16(a, b, c) __builtin_amdgcn_mfma_f32_16x16x32_bf16((a), (b), (c), 0, 0, 0)
#define MFMA32(a, b, c)    __builtin_amdgcn_mfma_f32_32x32x16_bf16((a), (b), (c), 0, 0, 0)

// async global->LDS, 16B/lane. LDS base wave-uniform; HW adds lane*16.
__device__ __forceinline__ void gload16(const __bf16* g, __bf16* l) {
  __builtin_amdgcn_global_load_lds((AS1 void*)(uintptr_t)g, (AS3 void*)l, 16, 0, 0);
}

__device__ __forceinline__ unsigned int cvtpk_bf16(float lo, float hi) {
  unsigned int r;
  asm("v_cvt_pk_bf16_f32 %0, %1, %2" : "=v"(r) : "v"(lo), "v"(hi));
  return r;
}

// v_permlane32_swap_b32 a, b : a[32:63] <-> b[0:31]
__device__ __forceinline__ void permswap(unsigned int& a, unsigned int& b) {
  asm volatile("v_permlane32_swap_b32 %0, %1" : "+v"(a), "+v"(b));
}

// ---------------- fp32 -> bf16 conversion (8 elems/thread) ----------------
__global__ void cvt_kernel(const float* __restrict__ s, __bf16* __restrict__ d, int n8) {
  int i = blockIdx.x * blockDim.x + threadIdx.x;
  const int stride = gridDim.x * blockDim.x;
  for (; i < n8; i += stride) {
    const float4* p = (const float4*)(s + (size_t)i * 8);
    float4 a = p[0], b = p[1];
    bf16x8 v;
    v[0] = (__bf16)a.x; v[1] = (__bf16)a.y; v[2] = (__bf16)a.z; v[3] = (__bf16)a.w;
    v[4] = (__bf16)b.x; v[5] = (__bf16)b.y; v[6] = (__bf16)b.z; v[7] = (__bf16)b.w;
    *(bf16x8*)(d + (size_t)i * 8) = v;
  }
}

// ---------------- mask all-zero? (mask is fp32) ----------------
__global__ void maskflag_kernel(const unsigned long long* __restrict__ m, int* __restrict__ flag) {
  const int n64 = 2048 * 2048 * 4 / 8;
  int idx = blockIdx.x * blockDim.x + threadIdx.x;
  bool nz = false;
  for (int i = idx; i < n64; i += gridDim.x * blockDim.x) nz |= (m[i] != 0ull);
  if (nz) atomicOr(flag, 1);
}

// ---------------- fused QGKV projection (bf16 in, bf16 out, fp32 acc) ----------------
__global__ __launch_bounds__(256) void proj_kernel(
    const __bf16* __restrict__ X,
    const __bf16* __restrict__ qw, const float* __restrict__ qb,
    const __bf16* __restrict__ kw, const float* __restrict__ kb,
    const __bf16* __restrict__ vw, const float* __restrict__ vb,
    __bf16* __restrict__ Qo, __bf16* __restrict__ Ko,
    __bf16* __restrict__ VTo, __bf16* __restrict__ Go)
{
  __shared__ __bf16 As[128][64];
  __shared__ __bf16 Bs[128][64];

  const int bid = blockIdx.x;
  const int r = bid >> 3;
  const int ntile = (bid & 7) * 4 + (r >> 5);
  const int mtile = r & 31;
  const int m0 = mtile * 128;
  const int n0 = ntile * 128;

  const __bf16* W; const float* bias; int nb;
  if (n0 < 2048)      { W = qw; bias = qb; nb = n0; }
  else if (n0 < 3072) { W = kw; bias = kb; nb = n0 - 2048; }
  else                { W = vw; bias = vb; nb = n0 - 3072; }

  const int tid = threadIdx.x;
  const int wv = tid >> 6, ln = tid & 63;
  const int wr = wv >> 1, wc = wv & 1;
  const int qr = ln & 15, qg = ln >> 4;
  const int lrow = ln >> 3, lcol = (ln & 7) * 8;

  f32x4 acc[4][4];
#pragma unroll
  for (int m = 0; m < 4; ++m)
#pragma unroll
    for (int n = 0; n < 4; ++n) acc[m][n] = 0.f;

  for (int k0 = 0; k0 < 1024; k0 += 64) {
#pragma unroll
    for (int i = 0; i < 4; ++i) {
      const int rb = i * 32 + wv * 8;
      gload16(X + (size_t)(m0 + rb + lrow) * 1024 + k0 + lcol, &As[rb][0]);
      gload16(W + (size_t)(nb + rb + lrow) * 1024 + k0 + lcol, &Bs[rb][0]);
    }
    __syncthreads();
#pragma unroll
    for (int kk = 0; kk < 2; ++kk) {
      bf16x8 af[4], bfv[4];
#pragma unroll
      for (int m = 0; m < 4; ++m) af[m] = *(const bf16x8*)&As[wr * 64 + m * 16 + qr][kk * 32 + qg * 8];
#pragma unroll
      for (int n = 0; n < 4; ++n) bfv[n] = *(const bf16x8*)&Bs[wc * 64 + n * 16 + qr][kk * 32 + qg * 8];
#pragma unroll
      for (int m = 0; m < 4; ++m)
#pragma unroll
        for (int n = 0; n < 4; ++n) acc[m][n] = MFMA_BF16(af[m], bfv[n], acc[m][n]);
    }
    __syncthreads();
  }

#pragma unroll
  for (int m = 0; m < 4; ++m) {
    const int gm0 = m0 + wr * 64 + m * 16 + qg * 4;
    const int b = gm0 >> 11;
    const int s = gm0 & 2047;
#pragma unroll
    for (int n = 0; n < 4; ++n) {
      const int nl = wc * 64 + n * 16 + qr;
      const float bb = bias[nb + nl];
      if (n0 < 1024) {            // Q -> [b,h,s,d]
        const int col = n0 + nl, hh = col >> 6, dd = col & 63;
        __bf16* dst = Qo + ((size_t)((b << 4) + hh)) * 131072 + (size_t)s * 64 + dd;
#pragma unroll
        for (int rr = 0; rr < 4; ++rr) dst[(size_t)rr * 64] = (__bf16)(acc[m][n][rr] + bb);
      } else if (n0 < 2048) {     // gate -> sigmoid -> [token, h*64+d]
        const int j = n0 - 1024 + nl;
        __bf16* dst = Go + (size_t)gm0 * 1024 + j;
#pragma unroll
        for (int rr = 0; rr < 4; ++rr) {
          const float v = acc[m][n][rr] + bb;
          dst[(size_t)rr * 1024] = (__bf16)(1.f / (1.f + __expf(-v)));
        }
      } else if (n0 < 3072) {     // K -> [b,h,s,d]
        const int j = n0 - 2048 + nl, hh = j >> 6, dd = j & 63;
        __bf16* dst = Ko + ((size_t)((b << 4) + hh)) * 131072 + (size_t)s * 64 + dd;
#pragma unroll
        for (int rr = 0; rr < 4; ++rr) dst[(size_t)rr * 64] = (__bf16)(acc[m][n][rr] + bb);
      } else {                    // V -> transposed [b,h,d,s]
        const int j = n0 - 3072 + nl, hh = j >> 6, dd = j & 63;
        bf16x4 pv;
#pragma unroll
        for (int rr = 0; rr < 4; ++rr) pv[rr] = (__bf16)(acc[m][n][rr] + bb);
        *(bf16x4*)(VTo + ((size_t)((b << 4) + hh)) * 131072 + (size_t)dd * 2048 + s) = pv;
      }
    }
  }
}

// ---------------- flash attention: swapped-QK^T, in-register softmax, no LDS ----------------
// 1 wave / 32 q-rows. 32x32x16 MFMA. Lane l: q = q0 + (l&31), hi = l>>5.
// Scores (mfma(K,Q)): lane holds S[kv=(r&3)+8(r>>2)+4hi][q] for r=0..15.
// PV (mfma(V^T,P)): O lane holds O[q][d=32*half+(r&3)+8(r>>2)+4hi].
__global__ __launch_bounds__(64) void attn_kernel(
    const __bf16* __restrict__ Qb, const __bf16* __restrict__ Kb,
    const __bf16* __restrict__ VT, const __bf16* __restrict__ G,
    const float* __restrict__ mask, const int* __restrict__ flag,
    __bf16* __restrict__ attn)
{
  const int bid = blockIdx.x;    // 2048 = 32 heads * 64 q-tiles
  const int y = bid >> 3;
  const int hl = (bid & 7) * 4 + (y >> 6);  // 4 heads per XCD
  const int q0 = (y & 63) * 32;
  const int ln = threadIdx.x;
  const int lq = ln & 31;
  const int hi = ln >> 5;
  const int b = hl >> 4, h = hl & 15;

  const __bf16* Qh = Qb + (size_t)hl * 131072;
  const __bf16* Kh = Kb + (size_t)hl * 131072;
  const __bf16* Vh = VT + (size_t)hl * 131072;

  // Q as B-operand: frag ks: Q[q0+lq][16ks + 8hi + 0..7]
  bf16x8 qf[4];
#pragma unroll
  for (int ks = 0; ks < 4; ++ks)
    qf[ks] = *(const bf16x8*)(Qh + (size_t)(q0 + lq) * 64 + ks * 16 + hi * 8);

  f32x16 o0, o1;
#pragma unroll
  for (int i = 0; i < 16; ++i) { o0[i] = 0.f; o1[i] = 0.f; }
  float mrun = -1e30f, lrun = 0.f;

  const bool um = (*flag) != 0;

  for (int kv0 = 0; kv0 < 2048; kv0 += 32) {
    // K as A-operand: frag ks: K[kv0+lq][16ks + 8hi + 0..7]
    bf16x8 kf[4];
#pragma unroll
    for (int ks = 0; ks < 4; ++ks)
      kf[ks] = *(const bf16x8*)(Kh + (size_t)(kv0 + lq) * 64 + ks * 16 + hi * 8);

    f32x16 s;
#pragma unroll
    for (int i = 0; i < 16; ++i) s[i] = 0.f;
#pragma unroll
    for (int ks = 0; ks < 4; ++ks) s = MFMA32(kf[ks], qf[ks], s);

    float p[16];
#pragma unroll
    for (int i = 0; i < 16; ++i) p[i] = s[i] * 0.125f;

    if (um) {
      const size_t mrow = (size_t)(q0 + lq) * 2048 + kv0;
#pragma unroll
      for (int i = 0; i < 16; ++i)
        p[i] += mask[mrow + (i & 3) + 8 * (i >> 2) + 4 * hi];
    }

    // row max over 32 kv: 15 local fmax + 1 cross-half shuffle
    float t = p[0];
#pragma unroll
    for (int i = 1; i < 16; ++i) t = fmaxf(t, p[i]);
    t = fmaxf(t, __shfl_xor(t, 32));
    const float mn = fmaxf(mrun, t);
    const float alpha = __expf(mrun - mn);
    mrun = mn;

    float ps = 0.f;
#pragma unroll
    for (int i = 0; i < 16; ++i) { p[i] = __expf(p[i] - mn); ps += p[i]; }
    ps += __shfl_xor(ps, 32);
    lrun = lrun * alpha + ps;

#pragma unroll
    for (int i = 0; i < 16; ++i) { o0[i] *= alpha; o1[i] *= alpha; }

    // pack P into B-frag layout: pa[ks] holds P[q=lq][kv0 + 16ks + 8hi + 0..7]
    bf16x8 pa[2];
#pragma unroll
    for (int ks = 0; ks < 2; ++ks) {
      unsigned int c0 = cvtpk_bf16(p[8 * ks + 0], p[8 * ks + 1]);
      unsigned int c1 = cvtpk_bf16(p[8 * ks + 2], p[8 * ks + 3]);
      unsigned int c2 = cvtpk_bf16(p[8 * ks + 4], p[8 * ks + 5]);
      unsigned int c3 = cvtpk_bf16(p[8 * ks + 6], p[8 * ks + 7]);
      permswap(c0, c2);  // c0 -> word0, c2 -> word2 (both halves)
      permswap(c1, c3);  // c1 -> word1, c3 -> word3
      u32x4 w; w.x = c0; w.y = c1; w.z = c2; w.w = c3;
      pa[ks] = __builtin_bit_cast(bf16x8, w);
    }

    // PV: V^T as A-operand (rows=d), P as B-operand (cols=q)
#pragma unroll
    for (int ks = 0; ks < 2; ++ks) {
      bf16x8 v0 = *(const bf16x8*)(Vh + (size_t)lq * 2048 + kv0 + ks * 16 + hi * 8);
      bf16x8 v1 = *(const bf16x8*)(Vh + (size_t)(32 + lq) * 2048 + kv0 + ks * 16 + hi * 8);
      o0 = MFMA32(v0, pa[ks], o0);
      o1 = MFMA32(v1, pa[ks], o1);
    }
  }

  // epilogue: 1/l, gate, store. Lane l: q fixed, d = 32*half + 8g + 4hi + j
  const float inv = 1.f / lrun;
  const size_t base = ((size_t)(b * 2048 + q0 + lq)) * 1024 + h * 64;
#pragma unroll
  for (int half = 0; half < 2; ++half) {
#pragma unroll
    for (int g = 0; g < 4; ++g) {
      const int d0 = half * 32 + g * 8 + hi * 4;
      bf16x4 g4 = *(const bf16x4*)(G + base + d0);
      bf16x4 r4;
#pragma unroll
      for (int j = 0; j < 4; ++j) {
        const float ov = half ? o1[g * 4 + j] : o0[g * 4 + j];
        r4[j] = (__bf16)(ov * inv * (float)g4[j]);
      }
      *(bf16x4*)(attn + base + d0) = r4;
    }
  }
}

// ---------------- O projection (bf16 in, fp32 out) ----------------
__global__ __launch_bounds__(256) void oproj_kernel(
    const __bf16* __restrict__ A, const __bf16* __restrict__ ow,
    const float* __restrict__ ob, float* __restrict__ C)
{
  __shared__ __bf16 As[128][64];
  __shared__ __bf16 Bs[128][64];
  const int bid = blockIdx.x;
  const int ntile = bid & 7;
  const int mtile = bid >> 3;
  const int m0 = mtile * 128, n0 = ntile * 128;

  const int tid = threadIdx.x;
  const int wv = tid >> 6, ln = tid & 63;
  const int wr = wv >> 1, wc = wv & 1;
  const int qr = ln & 15, qg = ln >> 4;
  const int lrow = ln >> 3, lcol = (ln & 7) * 8;

  f32x4 acc[4][4];
#pragma unroll
  for (int m = 0; m < 4; ++m)
#pragma unroll
    for (int n = 0; n < 4; ++n) acc[m][n] = 0.f;

  for (int k0 = 0; k0 < 1024; k0 += 64) {
#pragma unroll
    for (int i = 0; i < 4; ++i) {
      const int rb = i * 32 + wv * 8;
      gload16(A + (size_t)(m0 + rb + lrow) * 1024 + k0 + lcol, &As[rb][0]);
      gload16(ow + (size_t)(n0 + rb + lrow) * 1024 + k0 + lcol, &Bs[rb][0]);
    }
    __syncthreads();
#pragma unroll
    for (int kk = 0; kk < 2; ++kk) {
      bf16x8 af[4], bfv[4];
#pragma unroll
      for (int m = 0; m < 4; ++m) af[m] = *(const bf16x8*)&As[wr * 64 + m * 16 + qr][kk * 32 + qg * 8];
#pragma unroll
      for (int n = 0; n < 4; ++n) bfv[n] = *(const bf16x8*)&Bs[wc * 64 + n * 16 + qr][kk * 32 + qg * 8];
#pragma unroll
      for (int m = 0; m < 4; ++m)
#pragma unroll
        for (int n = 0; n < 4; ++n) acc[m][n] = MFMA_BF16(af[m], bfv[n], acc[m][n]);
    }
    __syncthreads();
  }

#pragma unroll
  for (int m = 0; m < 4; ++m) {
    const int gm0 = m0 + wr * 64 + m * 16 + qg * 4;
#pragma unroll
    for (int n = 0; n < 4; ++n) {
      const int gn = n0 + wc * 64 + n * 16 + qr;
      const float bb = ob[gn];
      float* dst = C + (size_t)gm0 * 1024 + gn;
#pragma unroll
      for (int rr = 0; rr < 4; ++rr) dst[(size_t)rr * 1024] = acc[m][n][rr] + bb;
    }
  }
}

extern "C" void kernel_launch(void* const* d_in, const int* in_sizes, int n_in,
                              void* d_out, int out_size, void* d_ws, size_t ws_size,
                              hipStream_t stream)
{
  const float* hs   = (const float*)d_in[0];
  const float* mask = (const float*)d_in[1];
  const float* qw   = (const float*)d_in[2];
  const float* qb   = (const float*)d_in[3];
  const float* kw   = (const float*)d_in[4];
  const float* kb   = (const float*)d_in[5];
  const float* vw   = (const float*)d_in[6];
  const float* vb   = (const float*)d_in[7];
  const float* ow   = (const float*)d_in[8];
  const float* ob   = (const float*)d_in[9];
  float* out = (float*)d_out;

  char* w = (char*)d_ws;
  int*    flag = (int*)w;
  __bf16* Xb  = (__bf16*)(w + 256);
  __bf16* qwb = Xb  + 4194304;
  __bf16* kwb = qwb + 2097152;
  __bf16* vwb = kwb + 1048576;
  __bf16* owb = vwb + 1048576;
  __bf16* Qo  = owb + 1048576;
  __bf16* Ko  = Qo  + 4194304;
  __bf16* VTo = Ko  + 4194304;
  __bf16* Go  = VTo + 4194304;
  __bf16* At  = Go  + 4194304;

  hipMemsetAsync(flag, 0, sizeof(int), stream);
  cvt_kernel<<<1024, 256, 0, stream>>>(hs, Xb,  4194304 / 8);
  cvt_kernel<<<512,  256, 0, stream>>>(qw, qwb, 2097152 / 8);
  cvt_kernel<<<512,  256, 0, stream>>>(kw, kwb, 1048576 / 8);
  cvt_kernel<<<512,  256, 0, stream>>>(vw, vwb, 1048576 / 8);
  cvt_kernel<<<512,  256, 0, stream>>>(ow, owb, 1048576 / 8);
  maskflag_kernel<<<512, 256, 0, stream>>>((const unsigned long long*)mask, flag);
  proj_kernel<<<1024, 256, 0, stream>>>(Xb, qwb, qb, kwb, kb, vwb, vb, Qo, Ko, VTo, Go);
  attn_kernel<<<2048, 64, 0, stream>>>(Qo, Ko, VTo, Go, mask, flag, At);
  oproj_kernel<<<256, 256, 0, stream>>>(At, owb, ob, out);
}

// Round 6
// 232.216 us; speedup vs baseline: 1.5087x; 1.0239x over previous
//
#include <hip/hip_runtime.h>
#include <cstdint>
#include <cstddef>

#define AS1 __attribute__((address_space(1)))
#define AS3 __attribute__((address_space(3)))

typedef __bf16 bf16x8 __attribute__((ext_vector_type(8)));
typedef __bf16 bf16x4 __attribute__((ext_vector_type(4)));
typedef float  f32x4  __attribute__((ext_vector_type(4)));
typedef float  f32x16 __attribute__((ext_vector_type(16)));
typedef unsigned int u32x4 __attribute__((ext_vector_type(4)));

#define MFMA_BF16(a, b, c) __builtin_amdgcn_mfma_f32_16x16x32_bf16((a), (b), (c), 0, 0, 0)
#define MFMA32(a, b, c)    __builtin_amdgcn_mfma_f32_32x32x16_bf16((a), (b), (c), 0, 0, 0)

// async global->LDS, 16B/lane. LDS base wave-uniform; HW adds lane*16.
__device__ __forceinline__ void gload16(const __bf16* g, __bf16* l) {
  __builtin_amdgcn_global_load_lds((AS1 void*)(uintptr_t)g, (AS3 void*)l, 16, 0, 0);
}

__device__ __forceinline__ unsigned int cvtpk_bf16(float lo, float hi) {
  unsigned int r;
  asm("v_cvt_pk_bf16_f32 %0, %1, %2" : "=v"(r) : "v"(lo), "v"(hi));
  return r;
}

// v_permlane32_swap_b32 a, b : a[32:63] <-> b[0:31]
__device__ __forceinline__ void permswap(unsigned int& a, unsigned int& b) {
  asm volatile("v_permlane32_swap_b32 %0, %1" : "+v"(a), "+v"(b));
}

// ---------------- fp32 -> bf16 conversion, all 5 tensors in one launch ----------------
__global__ void cvt_all_kernel(
    const float* __restrict__ hs, const float* __restrict__ qw, const float* __restrict__ kw,
    const float* __restrict__ vw, const float* __restrict__ ow,
    __bf16* __restrict__ Xb, __bf16* __restrict__ qwb, __bf16* __restrict__ kwb,
    __bf16* __restrict__ vwb, __bf16* __restrict__ owb)
{
  int i = blockIdx.x * blockDim.x + threadIdx.x;
  const int stride = gridDim.x * blockDim.x;
  for (; i < 1179648; i += stride) {
    const float* s; __bf16* d; int o;
    if (i < 524288)       { s = hs; d = Xb;  o = i; }
    else if (i < 786432)  { s = qw; d = qwb; o = i - 524288; }
    else if (i < 917504)  { s = kw; d = kwb; o = i - 786432; }
    else if (i < 1048576) { s = vw; d = vwb; o = i - 917504; }
    else                  { s = ow; d = owb; o = i - 1048576; }
    const float4* p = (const float4*)(s + (size_t)o * 8);
    float4 a = p[0], b = p[1];
    bf16x8 v;
    v[0] = (__bf16)a.x; v[1] = (__bf16)a.y; v[2] = (__bf16)a.z; v[3] = (__bf16)a.w;
    v[4] = (__bf16)b.x; v[5] = (__bf16)b.y; v[6] = (__bf16)b.z; v[7] = (__bf16)b.w;
    *(bf16x8*)(d + (size_t)o * 8) = v;
  }
}

// ---------------- mask all-zero? (mask is fp32) ----------------
__global__ void maskflag_kernel(const unsigned long long* __restrict__ m, int* __restrict__ flag) {
  const int n64 = 2048 * 2048 * 4 / 8;
  int idx = blockIdx.x * blockDim.x + threadIdx.x;
  bool nz = false;
  for (int i = idx; i < n64; i += gridDim.x * blockDim.x) nz |= (m[i] != 0ull);
  if (nz) atomicOr(flag, 1);
}

// ---------------- fused QGKV projection (bf16 in, bf16 out, fp32 acc) ----------------
__global__ __launch_bounds__(256) void proj_kernel(
    const __bf16* __restrict__ X,
    const __bf16* __restrict__ qw, const float* __restrict__ qb,
    const __bf16* __restrict__ kw, const float* __restrict__ kb,
    const __bf16* __restrict__ vw, const float* __restrict__ vb,
    __bf16* __restrict__ Qo, __bf16* __restrict__ Ko,
    __bf16* __restrict__ VTo, __bf16* __restrict__ Go)
{
  __shared__ __bf16 As[128][64];
  __shared__ __bf16 Bs[128][64];

  const int bid = blockIdx.x;
  const int r = bid >> 3;
  const int ntile = (bid & 7) * 4 + (r >> 5);
  const int mtile = r & 31;
  const int m0 = mtile * 128;
  const int n0 = ntile * 128;

  const __bf16* W; const float* bias; int nb;
  if (n0 < 2048)      { W = qw; bias = qb; nb = n0; }
  else if (n0 < 3072) { W = kw; bias = kb; nb = n0 - 2048; }
  else                { W = vw; bias = vb; nb = n0 - 3072; }

  const int tid = threadIdx.x;
  const int wv = tid >> 6, ln = tid & 63;
  const int wr = wv >> 1, wc = wv & 1;
  const int qr = ln & 15, qg = ln >> 4;
  const int lrow = ln >> 3, lcol = (ln & 7) * 8;

  f32x4 acc[4][4];
#pragma unroll
  for (int m = 0; m < 4; ++m)
#pragma unroll
    for (int n = 0; n < 4; ++n) acc[m][n] = 0.f;

  for (int k0 = 0; k0 < 1024; k0 += 64) {
#pragma unroll
    for (int i = 0; i < 4; ++i) {
      const int rb = i * 32 + wv * 8;
      gload16(X + (size_t)(m0 + rb + lrow) * 1024 + k0 + lcol, &As[rb][0]);
      gload16(W + (size_t)(nb + rb + lrow) * 1024 + k0 + lcol, &Bs[rb][0]);
    }
    __syncthreads();
#pragma unroll
    for (int kk = 0; kk < 2; ++kk) {
      bf16x8 af[4], bfv[4];
#pragma unroll
      for (int m = 0; m < 4; ++m) af[m] = *(const bf16x8*)&As[wr * 64 + m * 16 + qr][kk * 32 + qg * 8];
#pragma unroll
      for (int n = 0; n < 4; ++n) bfv[n] = *(const bf16x8*)&Bs[wc * 64 + n * 16 + qr][kk * 32 + qg * 8];
#pragma unroll
      for (int m = 0; m < 4; ++m)
#pragma unroll
        for (int n = 0; n < 4; ++n) acc[m][n] = MFMA_BF16(af[m], bfv[n], acc[m][n]);
    }
    __syncthreads();
  }

#pragma unroll
  for (int m = 0; m < 4; ++m) {
    const int gm0 = m0 + wr * 64 + m * 16 + qg * 4;
    const int b = gm0 >> 11;
    const int s = gm0 & 2047;
#pragma unroll
    for (int n = 0; n < 4; ++n) {
      const int nl = wc * 64 + n * 16 + qr;
      const float bb = bias[nb + nl];
      if (n0 < 1024) {            // Q -> [b,h,s,d]
        const int col = n0 + nl, hh = col >> 6, dd = col & 63;
        __bf16* dst = Qo + ((size_t)((b << 4) + hh)) * 131072 + (size_t)s * 64 + dd;
#pragma unroll
        for (int rr = 0; rr < 4; ++rr) dst[(size_t)rr * 64] = (__bf16)(acc[m][n][rr] + bb);
      } else if (n0 < 2048) {     // gate -> sigmoid -> [token, h*64+d]
        const int j = n0 - 1024 + nl;
        __bf16* dst = Go + (size_t)gm0 * 1024 + j;
#pragma unroll
        for (int rr = 0; rr < 4; ++rr) {
          const float v = acc[m][n][rr] + bb;
          dst[(size_t)rr * 1024] = (__bf16)(1.f / (1.f + __expf(-v)));
        }
      } else if (n0 < 3072) {     // K -> [b,h,s,d]
        const int j = n0 - 2048 + nl, hh = j >> 6, dd = j & 63;
        __bf16* dst = Ko + ((size_t)((b << 4) + hh)) * 131072 + (size_t)s * 64 + dd;
#pragma unroll
        for (int rr = 0; rr < 4; ++rr) dst[(size_t)rr * 64] = (__bf16)(acc[m][n][rr] + bb);
      } else {                    // V -> transposed [b,h,d,s]
        const int j = n0 - 3072 + nl, hh = j >> 6, dd = j & 63;
        bf16x4 pv;
#pragma unroll
        for (int rr = 0; rr < 4; ++rr) pv[rr] = (__bf16)(acc[m][n][rr] + bb);
        *(bf16x4*)(VTo + ((size_t)((b << 4) + hh)) * 131072 + (size_t)dd * 2048 + s) = pv;
      }
    }
  }
}

// ---------------- flash attention: swapped-QK^T, in-register softmax, split-KV x2 ----------------
// Block = 2 waves, one (head, 32-q-tile). Wave w: kv in [w*1024, w*1024+1024).
// Lane l: q = q0 + (l&31), hi = l>>5.
// Scores (mfma(K,Q)): lane holds S[kv=(r&3)+8(r>>2)+4hi][q].
// PV (mfma(V^T,P)): lane holds O[d=32*half+(r&3)+8(r>>2)+4hi][q].
__global__ __launch_bounds__(128, 4) void attn_kernel(
    const __bf16* __restrict__ Qb, const __bf16* __restrict__ Kb,
    const __bf16* __restrict__ VT, const __bf16* __restrict__ G,
    const float* __restrict__ mask, const int* __restrict__ flag,
    __bf16* __restrict__ attn)
{
  __shared__ float Ol[2][64][32];  // [wave][d][q] partial O
  __shared__ float Ml[2][32], Ll[2][32];

  const int bid = blockIdx.x;    // 2048 = 32 heads * 64 q-tiles
  const int y = bid >> 3;
  const int hl = (bid & 7) * 4 + (y >> 6);  // 4 heads per XCD
  const int q0 = (y & 63) * 32;
  const int tid = threadIdx.x;
  const int wid = tid >> 6;      // 0/1: kv-half
  const int ln = tid & 63;
  const int lq = ln & 31;
  const int hi = ln >> 5;
  const int b = hl >> 4, h = hl & 15;

  const __bf16* Qh = Qb + (size_t)hl * 131072;
  const __bf16* Kh = Kb + (size_t)hl * 131072;
  const __bf16* Vh = VT + (size_t)hl * 131072;

  // Q as B-operand: frag ks: Q[q0+lq][16ks + 8hi + 0..7]
  bf16x8 qf[4];
#pragma unroll
  for (int ks = 0; ks < 4; ++ks)
    qf[ks] = *(const bf16x8*)(Qh + (size_t)(q0 + lq) * 64 + ks * 16 + hi * 8);

  f32x16 o0, o1;
#pragma unroll
  for (int i = 0; i < 16; ++i) { o0[i] = 0.f; o1[i] = 0.f; }
  float mrun = -1e30f, lrun = 0.f;

  const bool um = (*flag) != 0;
  const int kvbeg = wid * 1024;

  for (int kv0 = kvbeg; kv0 < kvbeg + 1024; kv0 += 32) {
    bf16x8 kf[4];
#pragma unroll
    for (int ks = 0; ks < 4; ++ks)
      kf[ks] = *(const bf16x8*)(Kh + (size_t)(kv0 + lq) * 64 + ks * 16 + hi * 8);

    f32x16 s;
#pragma unroll
    for (int i = 0; i < 16; ++i) s[i] = 0.f;
#pragma unroll
    for (int ks = 0; ks < 4; ++ks) s = MFMA32(kf[ks], qf[ks], s);

    float p[16];
#pragma unroll
    for (int i = 0; i < 16; ++i) p[i] = s[i] * 0.125f;

    if (um) {
      const size_t mrow = (size_t)(q0 + lq) * 2048 + kv0;
#pragma unroll
      for (int i = 0; i < 16; ++i)
        p[i] += mask[mrow + (i & 3) + 8 * (i >> 2) + 4 * hi];
    }

    // row max over 32 kv: 15 local fmax + 1 cross-half shuffle
    float t = p[0];
#pragma unroll
    for (int i = 1; i < 16; ++i) t = fmaxf(t, p[i]);
    t = fmaxf(t, __shfl_xor(t, 32));
    const float mn = fmaxf(mrun, t);
    const float alpha = __expf(mrun - mn);
    mrun = mn;

    float ps = 0.f;
#pragma unroll
    for (int i = 0; i < 16; ++i) { p[i] = __expf(p[i] - mn); ps += p[i]; }
    ps += __shfl_xor(ps, 32);
    lrun = lrun * alpha + ps;

#pragma unroll
    for (int i = 0; i < 16; ++i) { o0[i] *= alpha; o1[i] *= alpha; }

    // pack P into B-frag layout: pa[ks] holds P[q=lq][kv0 + 16ks + 8hi + 0..7]
    bf16x8 pa[2];
#pragma unroll
    for (int ks = 0; ks < 2; ++ks) {
      unsigned int c0 = cvtpk_bf16(p[8 * ks + 0], p[8 * ks + 1]);
      unsigned int c1 = cvtpk_bf16(p[8 * ks + 2], p[8 * ks + 3]);
      unsigned int c2 = cvtpk_bf16(p[8 * ks + 4], p[8 * ks + 5]);
      unsigned int c3 = cvtpk_bf16(p[8 * ks + 6], p[8 * ks + 7]);
      permswap(c0, c2);
      permswap(c1, c3);
      u32x4 w; w.x = c0; w.y = c1; w.z = c2; w.w = c3;
      pa[ks] = __builtin_bit_cast(bf16x8, w);
    }

    // PV: V^T as A-operand (rows=d), P as B-operand (cols=q)
#pragma unroll
    for (int ks = 0; ks < 2; ++ks) {
      bf16x8 v0 = *(const bf16x8*)(Vh + (size_t)lq * 2048 + kv0 + ks * 16 + hi * 8);
      bf16x8 v1 = *(const bf16x8*)(Vh + (size_t)(32 + lq) * 2048 + kv0 + ks * 16 + hi * 8);
      o0 = MFMA32(v0, pa[ks], o0);
      o1 = MFMA32(v1, pa[ks], o1);
    }
  }

  // dump partials to LDS
#pragma unroll
  for (int r = 0; r < 16; ++r) {
    const int d = (r & 3) + 8 * (r >> 2) + 4 * hi;
    Ol[wid][d][lq] = o0[r];
    Ol[wid][d + 32][lq] = o1[r];
  }
  if (hi == 0) { Ml[wid][lq] = mrun; Ll[wid][lq] = lrun; }
  __syncthreads();

  // combine: 128 threads, each handles q = tid&31, d in [seg*16, seg*16+16)
  {
    const int q = tid & 31;
    const int seg = tid >> 5;  // 0..3
    const float m0 = Ml[0][q], m1 = Ml[1][q];
    const float M = fmaxf(m0, m1);
    const float e0 = __expf(m0 - M), e1 = __expf(m1 - M);
    const float L = e0 * Ll[0][q] + e1 * Ll[1][q];
    const float inv = 1.f / L;
    const size_t base = ((size_t)(b * 2048 + q0 + q)) * 1024 + h * 64 + seg * 16;
    bf16x8 g0 = *(const bf16x8*)(G + base);
    bf16x8 g1 = *(const bf16x8*)(G + base + 8);
    bf16x8 r0, r1;
#pragma unroll
    for (int j = 0; j < 8; ++j) {
      const int d = seg * 16 + j;
      const float sacc = e0 * Ol[0][d][q] + e1 * Ol[1][d][q];
      r0[j] = (__bf16)(sacc * inv * (float)g0[j]);
    }
#pragma unroll
    for (int j = 0; j < 8; ++j) {
      const int d = seg * 16 + 8 + j;
      const float sacc = e0 * Ol[0][d][q] + e1 * Ol[1][d][q];
      r1[j] = (__bf16)(sacc * inv * (float)g1[j]);
    }
    *(bf16x8*)(attn + base) = r0;
    *(bf16x8*)(attn + base + 8) = r1;
  }
}

// ---------------- O projection (bf16 in, fp32 out) ----------------
__global__ __launch_bounds__(256) void oproj_kernel(
    const __bf16* __restrict__ A, const __bf16* __restrict__ ow,
    const float* __restrict__ ob, float* __restrict__ C)
{
  __shared__ __bf16 As[128][64];
  __shared__ __bf16 Bs[128][64];
  const int bid = blockIdx.x;
  const int ntile = bid & 7;
  const int mtile = bid >> 3;
  const int m0 = mtile * 128, n0 = ntile * 128;

  const int tid = threadIdx.x;
  const int wv = tid >> 6, ln = tid & 63;
  const int wr = wv >> 1, wc = wv & 1;
  const int qr = ln & 15, qg = ln >> 4;
  const int lrow = ln >> 3, lcol = (ln & 7) * 8;

  f32x4 acc[4][4];
#pragma unroll
  for (int m = 0; m < 4; ++m)
#pragma unroll
    for (int n = 0; n < 4; ++n) acc[m][n] = 0.f;

  for (int k0 = 0; k0 < 1024; k0 += 64) {
#pragma unroll
    for (int i = 0; i < 4; ++i) {
      const int rb = i * 32 + wv * 8;
      gload16(A + (size_t)(m0 + rb + lrow) * 1024 + k0 + lcol, &As[rb][0]);
      gload16(ow + (size_t)(n0 + rb + lrow) * 1024 + k0 + lcol, &Bs[rb][0]);
    }
    __syncthreads();
#pragma unroll
    for (int kk = 0; kk < 2; ++kk) {
      bf16x8 af[4], bfv[4];
#pragma unroll
      for (int m = 0; m < 4; ++m) af[m] = *(const bf16x8*)&As[wr * 64 + m * 16 + qr][kk * 32 + qg * 8];
#pragma unroll
      for (int n = 0; n < 4; ++n) bfv[n] = *(const bf16x8*)&Bs[wc * 64 + n * 16 + qr][kk * 32 + qg * 8];
#pragma unroll
      for (int m = 0; m < 4; ++m)
#pragma unroll
        for (int n = 0; n < 4; ++n) acc[m][n] = MFMA_BF16(af[m], bfv[n], acc[m][n]);
    }
    __syncthreads();
  }

#pragma unroll
  for (int m = 0; m < 4; ++m) {
    const int gm0 = m0 + wr * 64 + m * 16 + qg * 4;
#pragma unroll
    for (int n = 0; n < 4; ++n) {
      const int gn = n0 + wc * 64 + n * 16 + qr;
      const float bb = ob[gn];
      float* dst = C + (size_t)gm0 * 1024 + gn;
#pragma unroll
      for (int rr = 0; rr < 4; ++rr) dst[(size_t)rr * 1024] = acc[m][n][rr] + bb;
    }
  }
}

extern "C" void kernel_launch(void* const* d_in, const int* in_sizes, int n_in,
                              void* d_out, int out_size, void* d_ws, size_t ws_size,
                              hipStream_t stream)
{
  const float* hs   = (const float*)d_in[0];
  const float* mask = (const float*)d_in[1];
  const float* qw   = (const float*)d_in[2];
  const float* qb   = (const float*)d_in[3];
  const float* kw   = (const float*)d_in[4];
  const float* kb   = (const float*)d_in[5];
  const float* vw   = (const float*)d_in[6];
  const float* vb   = (const float*)d_in[7];
  const float* ow   = (const float*)d_in[8];
  const float* ob   = (const float*)d_in[9];
  float* out = (float*)d_out;

  char* w = (char*)d_ws;
  int*    flag = (int*)w;
  __bf16* Xb  = (__bf16*)(w + 256);
  __bf16* qwb = Xb  + 4194304;
  __bf16* kwb = qwb + 2097152;
  __bf16* vwb = kwb + 1048576;
  __bf16* owb = vwb + 1048576;
  __bf16* Qo  = owb + 1048576;
  __bf16* Ko  = Qo  + 4194304;
  __bf16* VTo = Ko  + 4194304;
  __bf16* Go  = VTo + 4194304;
  __bf16* At  = Go  + 4194304;

  hipMemsetAsync(flag, 0, sizeof(int), stream);
  cvt_all_kernel<<<2048, 256, 0, stream>>>(hs, qw, kw, vw, ow, Xb, qwb, kwb, vwb, owb);
  maskflag_kernel<<<512, 256, 0, stream>>>((const unsigned long long*)mask, flag);
  proj_kernel<<<1024, 256, 0, stream>>>(Xb, qwb, qb, kwb, kb, vwb, vb, Qo, Ko, VTo, Go);
  attn_kernel<<<2048, 128, 0, stream>>>(Qo, Ko, VTo, Go, mask, flag, At);
  oproj_kernel<<<256, 256, 0, stream>>>(At, owb, ob, out);
}

// Round 7
// 172.195 us; speedup vs baseline: 2.0345x; 1.3486x over previous
//
#include <hip/hip_runtime.h>
#include <cstdint>
#include <cstddef>

#define AS1 __attribute__((address_space(1)))
#define AS3 __attribute__((address_space(3)))

typedef __bf16 bf16x8 __attribute__((ext_vector_type(8)));
typedef __bf16 bf16x4 __attribute__((ext_vector_type(4)));
typedef float  f32x4  __attribute__((ext_vector_type(4)));
typedef float  f32x16 __attribute__((ext_vector_type(16)));
typedef unsigned int u32x4 __attribute__((ext_vector_type(4)));

#define MFMA_BF16(a, b, c) __builtin_amdgcn_mfma_f32_16x16x32_bf16((a), (b), (c), 0, 0, 0)
#define MFMA32(a, b, c)    __builtin_amdgcn_mfma_f32_32x32x16_bf16((a), (b), (c), 0, 0, 0)

// async global->LDS, 16B/lane. LDS base wave-uniform; HW adds lane*16. Global addr per-lane.
__device__ __forceinline__ void gload16(const __bf16* g, __bf16* l) {
  __builtin_amdgcn_global_load_lds((AS1 void*)(uintptr_t)g, (AS3 void*)l, 16, 0, 0);
}

__device__ __forceinline__ unsigned int cvtpk_bf16(float lo, float hi) {
  unsigned int r;
  asm("v_cvt_pk_bf16_f32 %0, %1, %2" : "=v"(r) : "v"(lo), "v"(hi));
  return r;
}

// v_permlane32_swap_b32 a, b : a[32:63] <-> b[0:31]
__device__ __forceinline__ void permswap(unsigned int& a, unsigned int& b) {
  asm volatile("v_permlane32_swap_b32 %0, %1" : "+v"(a), "+v"(b));
}

// ---------------- fp32 -> bf16 conversion, all 5 tensors in one launch ----------------
__global__ void cvt_all_kernel(
    const float* __restrict__ hs, const float* __restrict__ qw, const float* __restrict__ kw,
    const float* __restrict__ vw, const float* __restrict__ ow,
    __bf16* __restrict__ Xb, __bf16* __restrict__ qwb, __bf16* __restrict__ kwb,
    __bf16* __restrict__ vwb, __bf16* __restrict__ owb)
{
  int i = blockIdx.x * blockDim.x + threadIdx.x;
  const int stride = gridDim.x * blockDim.x;
  for (; i < 1179648; i += stride) {
    const float* s; __bf16* d; int o;
    if (i < 524288)       { s = hs; d = Xb;  o = i; }
    else if (i < 786432)  { s = qw; d = qwb; o = i - 524288; }
    else if (i < 917504)  { s = kw; d = kwb; o = i - 786432; }
    else if (i < 1048576) { s = vw; d = vwb; o = i - 917504; }
    else                  { s = ow; d = owb; o = i - 1048576; }
    const float4* p = (const float4*)(s + (size_t)o * 8);
    float4 a = p[0], b = p[1];
    bf16x8 v;
    v[0] = (__bf16)a.x; v[1] = (__bf16)a.y; v[2] = (__bf16)a.z; v[3] = (__bf16)a.w;
    v[4] = (__bf16)b.x; v[5] = (__bf16)b.y; v[6] = (__bf16)b.z; v[7] = (__bf16)b.w;
    *(bf16x8*)(d + (size_t)o * 8) = v;
  }
}

// ---------------- mask all-zero? (mask is fp32) ----------------
__global__ void maskflag_kernel(const unsigned long long* __restrict__ m, int* __restrict__ flag) {
  const int n64 = 2048 * 2048 * 4 / 8;
  int idx = blockIdx.x * blockDim.x + threadIdx.x;
  bool nz = false;
  for (int i = idx; i < n64; i += gridDim.x * blockDim.x) nz |= (m[i] != 0ull);
  if (nz) atomicOr(flag, 1);
}

// ---------------- fused QGKV projection (bf16 in, bf16 out, fp32 acc) ----------------
__global__ __launch_bounds__(256) void proj_kernel(
    const __bf16* __restrict__ X,
    const __bf16* __restrict__ qw, const float* __restrict__ qb,
    const __bf16* __restrict__ kw, const float* __restrict__ kb,
    const __bf16* __restrict__ vw, const float* __restrict__ vb,
    __bf16* __restrict__ Qo, __bf16* __restrict__ Ko,
    __bf16* __restrict__ VTo, __bf16* __restrict__ Go)
{
  __shared__ __bf16 As[128][64];
  __shared__ __bf16 Bs[128][64];

  const int bid = blockIdx.x;
  const int r = bid >> 3;
  const int ntile = (bid & 7) * 4 + (r >> 5);
  const int mtile = r & 31;
  const int m0 = mtile * 128;
  const int n0 = ntile * 128;

  const __bf16* W; const float* bias; int nb;
  if (n0 < 2048)      { W = qw; bias = qb; nb = n0; }
  else if (n0 < 3072) { W = kw; bias = kb; nb = n0 - 2048; }
  else                { W = vw; bias = vb; nb = n0 - 3072; }

  const int tid = threadIdx.x;
  const int wv = tid >> 6, ln = tid & 63;
  const int wr = wv >> 1, wc = wv & 1;
  const int qr = ln & 15, qg = ln >> 4;
  const int lrow = ln >> 3, lcol = (ln & 7) * 8;

  f32x4 acc[4][4];
#pragma unroll
  for (int m = 0; m < 4; ++m)
#pragma unroll
    for (int n = 0; n < 4; ++n) acc[m][n] = 0.f;

  for (int k0 = 0; k0 < 1024; k0 += 64) {
#pragma unroll
    for (int i = 0; i < 4; ++i) {
      const int rb = i * 32 + wv * 8;
      gload16(X + (size_t)(m0 + rb + lrow) * 1024 + k0 + lcol, &As[rb][0]);
      gload16(W + (size_t)(nb + rb + lrow) * 1024 + k0 + lcol, &Bs[rb][0]);
    }
    __syncthreads();
#pragma unroll
    for (int kk = 0; kk < 2; ++kk) {
      bf16x8 af[4], bfv[4];
#pragma unroll
      for (int m = 0; m < 4; ++m) af[m] = *(const bf16x8*)&As[wr * 64 + m * 16 + qr][kk * 32 + qg * 8];
#pragma unroll
      for (int n = 0; n < 4; ++n) bfv[n] = *(const bf16x8*)&Bs[wc * 64 + n * 16 + qr][kk * 32 + qg * 8];
#pragma unroll
      for (int m = 0; m < 4; ++m)
#pragma unroll
        for (int n = 0; n < 4; ++n) acc[m][n] = MFMA_BF16(af[m], bfv[n], acc[m][n]);
    }
    __syncthreads();
  }

#pragma unroll
  for (int m = 0; m < 4; ++m) {
    const int gm0 = m0 + wr * 64 + m * 16 + qg * 4;
    const int b = gm0 >> 11;
    const int s = gm0 & 2047;
#pragma unroll
    for (int n = 0; n < 4; ++n) {
      const int nl = wc * 64 + n * 16 + qr;
      const float bb = bias[nb + nl];
      if (n0 < 1024) {            // Q -> [b,h,s,d], pre-scaled by 1/sqrt(d)
        const int col = n0 + nl, hh = col >> 6, dd = col & 63;
        __bf16* dst = Qo + ((size_t)((b << 4) + hh)) * 131072 + (size_t)s * 64 + dd;
#pragma unroll
        for (int rr = 0; rr < 4; ++rr) dst[(size_t)rr * 64] = (__bf16)((acc[m][n][rr] + bb) * 0.125f);
      } else if (n0 < 2048) {     // gate -> sigmoid -> [token, h*64+d]
        const int j = n0 - 1024 + nl;
        __bf16* dst = Go + (size_t)gm0 * 1024 + j;
#pragma unroll
        for (int rr = 0; rr < 4; ++rr) {
          const float v = acc[m][n][rr] + bb;
          dst[(size_t)rr * 1024] = (__bf16)(1.f / (1.f + __expf(-v)));
        }
      } else if (n0 < 3072) {     // K -> [b,h,s,d]
        const int j = n0 - 2048 + nl, hh = j >> 6, dd = j & 63;
        __bf16* dst = Ko + ((size_t)((b << 4) + hh)) * 131072 + (size_t)s * 64 + dd;
#pragma unroll
        for (int rr = 0; rr < 4; ++rr) dst[(size_t)rr * 64] = (__bf16)(acc[m][n][rr] + bb);
      } else {                    // V -> transposed [b,h,d,s]
        const int j = n0 - 3072 + nl, hh = j >> 6, dd = j & 63;
        bf16x4 pv;
#pragma unroll
        for (int rr = 0; rr < 4; ++rr) pv[rr] = (__bf16)(acc[m][n][rr] + bb);
        *(bf16x4*)(VTo + ((size_t)((b << 4) + hh)) * 131072 + (size_t)dd * 2048 + s) = pv;
      }
    }
  }
}

// ---------------- flash attention: LDS-staged K/V, swapped-QK^T, in-register softmax ----------------
// Block = 4 waves (256 thr) = one head, 128 q rows; wave w owns q0+w*32.
// K/V tiles (64 kv x 64 d) staged in LDS as [32 rows][256B] with 16B-granule XOR swizzle
// (b_phys = b_log ^ ((row&15)<<4)); staged via gload16 with pre-swizzled per-lane global src.
// Scores (mfma(K,Q)): lane holds S[kv=(r&3)+8(r>>2)+4hi][q=lq].
// PV (mfma(V^T,P)): lane holds O[d=32*half+(r&3)+8(r>>2)+4hi][q=lq].
__global__ __launch_bounds__(256, 2) void attn_kernel(
    const __bf16* __restrict__ Qb, const __bf16* __restrict__ Kb,
    const __bf16* __restrict__ VT, const __bf16* __restrict__ G,
    const float* __restrict__ mask, const int* __restrict__ flag,
    __bf16* __restrict__ attn)
{
  __shared__ __bf16 Ksh[32][128];  // [kv&31][ (kv>>5)*128B : d*2B ] swizzled, 8KB
  __shared__ __bf16 Vsh[32][128];  // [d&31][ (d>>5)*128B : kv*2B ] swizzled, 8KB

  const int bid = blockIdx.x;    // 512 = 8 xcd * (4 heads * 16 qblocks)
  const int y = bid >> 3;        // 0..63
  const int hl = (bid & 7) * 4 + (y >> 4);  // 4 heads per XCD
  const int tid = threadIdx.x;
  const int w = tid >> 6;        // wave 0..3
  const int ln = tid & 63;
  const int lq = ln & 31;
  const int hi = ln >> 5;
  const int q0 = (y & 15) * 128 + w * 32;
  const int b = hl >> 4, h = hl & 15;

  const __bf16* Qh = Qb + (size_t)hl * 131072;
  const __bf16* Kh = Kb + (size_t)hl * 131072;
  const __bf16* Vh = VT + (size_t)hl * 131072;

  // staging source offsets (elements within head), chunk-invariant parts
  int kco[2], vco[2], ldst[2];
#pragma unroll
  for (int i = 0; i < 2; ++i) {
    const int prow = w * 8 + i * 4 + (ln >> 4);  // physical LDS row 0..31
    const int bphys = (ln & 15) * 16;
    const int blog = bphys ^ ((prow & 15) << 4);
    const int half = blog >> 7;             // K: kv-half | V: d-half
    const int col = (blog & 127) >> 1;      // K: d | V: kv-local
    kco[i] = (half * 32 + prow) * 64 + col;
    vco[i] = (half * 32 + prow) * 2048 + col;
    ldst[i] = (w * 8 + i * 4) * 256;        // byte offset of instruction's LDS slab
  }
  const int swz = (lq & 15) << 4;
  const int krow = lq * 256;

  // Q as B-operand (pre-scaled by 1/8 in proj): frag ks: Q[q0+lq][16ks+8hi+0..7]
  bf16x8 qf[4];
#pragma unroll
  for (int ks = 0; ks < 4; ++ks)
    qf[ks] = *(const bf16x8*)(Qh + (size_t)(q0 + lq) * 64 + ks * 16 + hi * 8);

  f32x16 o0, o1;
#pragma unroll
  for (int i = 0; i < 16; ++i) { o0[i] = 0.f; o1[i] = 0.f; }
  float mrun = -1e30f, lrun = 0.f;

  const bool um = (*flag) != 0;

  for (int c = 0; c < 32; ++c) {
    const int kv0 = c * 64;
    // cooperative staging: 4KB/wave, coalesced 1KB instructions
#pragma unroll
    for (int i = 0; i < 2; ++i) {
      gload16(Kh + kv0 * 64 + kco[i], (__bf16*)((char*)&Ksh[0][0] + ldst[i]));
      gload16(Vh + kv0 + vco[i],      (__bf16*)((char*)&Vsh[0][0] + ldst[i]));
    }
    __syncthreads();

#pragma unroll
    for (int s32 = 0; s32 < 2; ++s32) {
      bf16x8 kf[4];
#pragma unroll
      for (int ks = 0; ks < 4; ++ks)
        kf[ks] = *(const bf16x8*)((const char*)&Ksh[0][0] + krow + ((s32 * 128 + ks * 32 + hi * 16) ^ swz));

      f32x16 s;
#pragma unroll
      for (int i = 0; i < 16; ++i) s[i] = 0.f;
#pragma unroll
      for (int ks = 0; ks < 4; ++ks) s = MFMA32(kf[ks], qf[ks], s);

      float p[16];
#pragma unroll
      for (int i = 0; i < 16; ++i) p[i] = s[i];

      if (um) {
        const size_t mrow = (size_t)(q0 + lq) * 2048 + kv0 + s32 * 32;
#pragma unroll
        for (int i = 0; i < 16; ++i)
          p[i] += mask[mrow + (i & 3) + 8 * (i >> 2) + 4 * hi];
      }

      // row max over 32 kv: 15 local fmax + 1 cross-half shuffle
      float t = p[0];
#pragma unroll
      for (int i = 1; i < 16; ++i) t = fmaxf(t, p[i]);
      t = fmaxf(t, __shfl_xor(t, 32));
      const float mn = fmaxf(mrun, t);
      const float alpha = __expf(mrun - mn);
      mrun = mn;

      float ps = 0.f;
#pragma unroll
      for (int i = 0; i < 16; ++i) { p[i] = __expf(p[i] - mn); ps += p[i]; }
      ps += __shfl_xor(ps, 32);
      lrun = lrun * alpha + ps;

#pragma unroll
      for (int i = 0; i < 16; ++i) { o0[i] *= alpha; o1[i] *= alpha; }

      // pack P into B-frag layout: pa[ks] holds P[q=lq][16ks + 8hi + 0..7]
      bf16x8 pa[2];
#pragma unroll
      for (int ks = 0; ks < 2; ++ks) {
        unsigned int c0 = cvtpk_bf16(p[8 * ks + 0], p[8 * ks + 1]);
        unsigned int c1 = cvtpk_bf16(p[8 * ks + 2], p[8 * ks + 3]);
        unsigned int c2 = cvtpk_bf16(p[8 * ks + 4], p[8 * ks + 5]);
        unsigned int c3 = cvtpk_bf16(p[8 * ks + 6], p[8 * ks + 7]);
        permswap(c0, c2);
        permswap(c1, c3);
        u32x4 wv; wv.x = c0; wv.y = c1; wv.z = c2; wv.w = c3;
        pa[ks] = __builtin_bit_cast(bf16x8, wv);
      }

      // PV from swizzled Vsh: V^T rows = d, cols = kv
#pragma unroll
      for (int ks = 0; ks < 2; ++ks) {
        const int kvb = s32 * 64 + ks * 32 + hi * 16;
        bf16x8 v0 = *(const bf16x8*)((const char*)&Vsh[0][0] + krow + ((0 + kvb) ^ swz));
        bf16x8 v1 = *(const bf16x8*)((const char*)&Vsh[0][0] + krow + ((128 + kvb) ^ swz));
        o0 = MFMA32(v0, pa[ks], o0);
        o1 = MFMA32(v1, pa[ks], o1);
      }
    }
    __syncthreads();
  }

  // epilogue: 1/l, gate, store. Lane: q=q0+lq fixed, d = 32*half + 8g + 4hi + j
  const float inv = 1.f / lrun;
  const size_t base = ((size_t)(b * 2048 + q0 + lq)) * 1024 + h * 64;
#pragma unroll
  for (int half = 0; half < 2; ++half) {
#pragma unroll
    for (int g = 0; g < 4; ++g) {
      const int d0 = half * 32 + g * 8 + hi * 4;
      bf16x4 g4 = *(const bf16x4*)(G + base + d0);
      bf16x4 r4;
#pragma unroll
      for (int j = 0; j < 4; ++j) {
        const float ov = half ? o1[g * 4 + j] : o0[g * 4 + j];
        r4[j] = (__bf16)(ov * inv * (float)g4[j]);
      }
      *(bf16x4*)(attn + base + d0) = r4;
    }
  }
}

// ---------------- O projection (bf16 in, fp32 out) ----------------
__global__ __launch_bounds__(256) void oproj_kernel(
    const __bf16* __restrict__ A, const __bf16* __restrict__ ow,
    const float* __restrict__ ob, float* __restrict__ C)
{
  __shared__ __bf16 As[128][64];
  __shared__ __bf16 Bs[128][64];
  const int bid = blockIdx.x;
  const int ntile = bid & 7;
  const int mtile = bid >> 3;
  const int m0 = mtile * 128, n0 = ntile * 128;

  const int tid = threadIdx.x;
  const int wv = tid >> 6, ln = tid & 63;
  const int wr = wv >> 1, wc = wv & 1;
  const int qr = ln & 15, qg = ln >> 4;
  const int lrow = ln >> 3, lcol = (ln & 7) * 8;

  f32x4 acc[4][4];
#pragma unroll
  for (int m = 0; m < 4; ++m)
#pragma unroll
    for (int n = 0; n < 4; ++n) acc[m][n] = 0.f;

  for (int k0 = 0; k0 < 1024; k0 += 64) {
#pragma unroll
    for (int i = 0; i < 4; ++i) {
      const int rb = i * 32 + wv * 8;
      gload16(A + (size_t)(m0 + rb + lrow) * 1024 + k0 + lcol, &As[rb][0]);
      gload16(ow + (size_t)(n0 + rb + lrow) * 1024 + k0 + lcol, &Bs[rb][0]);
    }
    __syncthreads();
#pragma unroll
    for (int kk = 0; kk < 2; ++kk) {
      bf16x8 af[4], bfv[4];
#pragma unroll
      for (int m = 0; m < 4; ++m) af[m] = *(const bf16x8*)&As[wr * 64 + m * 16 + qr][kk * 32 + qg * 8];
#pragma unroll
      for (int n = 0; n < 4; ++n) bfv[n] = *(const bf16x8*)&Bs[wc * 64 + n * 16 + qr][kk * 32 + qg * 8];
#pragma unroll
      for (int m = 0; m < 4; ++m)
#pragma unroll
        for (int n = 0; n < 4; ++n) acc[m][n] = MFMA_BF16(af[m], bfv[n], acc[m][n]);
    }
    __syncthreads();
  }

#pragma unroll
  for (int m = 0; m < 4; ++m) {
    const int gm0 = m0 + wr * 64 + m * 16 + qg * 4;
#pragma unroll
    for (int n = 0; n < 4; ++n) {
      const int gn = n0 + wc * 64 + n * 16 + qr;
      const float bb = ob[gn];
      float* dst = C + (size_t)gm0 * 1024 + gn;
#pragma unroll
      for (int rr = 0; rr < 4; ++rr) dst[(size_t)rr * 1024] = acc[m][n][rr] + bb;
    }
  }
}

extern "C" void kernel_launch(void* const* d_in, const int* in_sizes, int n_in,
                              void* d_out, int out_size, void* d_ws, size_t ws_size,
                              hipStream_t stream)
{
  const float* hs   = (const float*)d_in[0];
  const float* mask = (const float*)d_in[1];
  const float* qw   = (const float*)d_in[2];
  const float* qb   = (const float*)d_in[3];
  const float* kw   = (const float*)d_in[4];
  const float* kb   = (const float*)d_in[5];
  const float* vw   = (const float*)d_in[6];
  const float* vb   = (const float*)d_in[7];
  const float* ow   = (const float*)d_in[8];
  const float* ob   = (const float*)d_in[9];
  float* out = (float*)d_out;

  char* w = (char*)d_ws;
  int*    flag = (int*)w;
  __bf16* Xb  = (__bf16*)(w + 256);
  __bf16* qwb = Xb  + 4194304;
  __bf16* kwb = qwb + 2097152;
  __bf16* vwb = kwb + 1048576;
  __bf16* owb = vwb + 1048576;
  __bf16* Qo  = owb + 1048576;
  __bf16* Ko  = Qo  + 4194304;
  __bf16* VTo = Ko  + 4194304;
  __bf16* Go  = VTo + 4194304;
  __bf16* At  = Go  + 4194304;

  hipMemsetAsync(flag, 0, sizeof(int), stream);
  cvt_all_kernel<<<2048, 256, 0, stream>>>(hs, qw, kw, vw, ow, Xb, qwb, kwb, vwb, owb);
  maskflag_kernel<<<512, 256, 0, stream>>>((const unsigned long long*)mask, flag);
  proj_kernel<<<1024, 256, 0, stream>>>(Xb, qwb, qb, kwb, kb, vwb, vb, Qo, Ko, VTo, Go);
  attn_kernel<<<512, 256, 0, stream>>>(Qo, Ko, VTo, Go, mask, flag, At);
  oproj_kernel<<<256, 256, 0, stream>>>(At, owb, ob, out);
}

// Round 8
// 153.428 us; speedup vs baseline: 2.2834x; 1.1223x over previous
//
#include <hip/hip_runtime.h>
#include <cstdint>
#include <cstddef>

#define AS1 __attribute__((address_space(1)))
#define AS3 __attribute__((address_space(3)))

typedef __bf16 bf16x8 __attribute__((ext_vector_type(8)));
typedef __bf16 bf16x4 __attribute__((ext_vector_type(4)));
typedef float  f32x4  __attribute__((ext_vector_type(4)));
typedef float  f32x16 __attribute__((ext_vector_type(16)));
typedef unsigned int u32x4 __attribute__((ext_vector_type(4)));

#define MFMA_BF16(a, b, c) __builtin_amdgcn_mfma_f32_16x16x32_bf16((a), (b), (c), 0, 0, 0)
#define MFMA32(a, b, c)    __builtin_amdgcn_mfma_f32_32x32x16_bf16((a), (b), (c), 0, 0, 0)

// async global->LDS, 16B/lane. LDS base wave-uniform; HW adds lane*16. Global addr per-lane.
__device__ __forceinline__ void gload16(const __bf16* g, __bf16* l) {
  __builtin_amdgcn_global_load_lds((AS1 void*)(uintptr_t)g, (AS3 void*)l, 16, 0, 0);
}

__device__ __forceinline__ unsigned int cvtpk_bf16(float lo, float hi) {
  unsigned int r;
  asm("v_cvt_pk_bf16_f32 %0, %1, %2" : "=v"(r) : "v"(lo), "v"(hi));
  return r;
}

// v_permlane32_swap_b32 a, b : a[32:63] <-> b[0:31]
__device__ __forceinline__ void permswap(unsigned int& a, unsigned int& b) {
  asm volatile("v_permlane32_swap_b32 %0, %1" : "+v"(a), "+v"(b));
}

// ---------------- fp32 -> bf16 conversion (5 tensors) + mask-zero scan, one launch ----------------
__global__ void cvt_all_kernel(
    const float* __restrict__ hs, const float* __restrict__ qw, const float* __restrict__ kw,
    const float* __restrict__ vw, const float* __restrict__ ow,
    __bf16* __restrict__ Xb, __bf16* __restrict__ qwb, __bf16* __restrict__ kwb,
    __bf16* __restrict__ vwb, __bf16* __restrict__ owb,
    const unsigned long long* __restrict__ mask, int* __restrict__ flag)
{
  const int gid = blockIdx.x * blockDim.x + threadIdx.x;
  const int stride = gridDim.x * blockDim.x;
  for (int i = gid; i < 1179648; i += stride) {
    const float* s; __bf16* d; int o;
    if (i < 524288)       { s = hs; d = Xb;  o = i; }
    else if (i < 786432)  { s = qw; d = qwb; o = i - 524288; }
    else if (i < 917504)  { s = kw; d = kwb; o = i - 786432; }
    else if (i < 1048576) { s = vw; d = vwb; o = i - 917504; }
    else                  { s = ow; d = owb; o = i - 1048576; }
    const float4* p = (const float4*)(s + (size_t)o * 8);
    float4 a = p[0], b = p[1];
    bf16x8 v;
    v[0] = (__bf16)a.x; v[1] = (__bf16)a.y; v[2] = (__bf16)a.z; v[3] = (__bf16)a.w;
    v[4] = (__bf16)b.x; v[5] = (__bf16)b.y; v[6] = (__bf16)b.z; v[7] = (__bf16)b.w;
    *(bf16x8*)(d + (size_t)o * 8) = v;
  }
  bool nz = false;
  for (int i = gid; i < 2097152; i += stride) nz |= (mask[i] != 0ull);
  if (nz) atomicOr(flag, 1);
}

// ---------------- fused QGKV projection (bf16 in, bf16 out, fp32 acc), 2-phase dbuf ----------------
__global__ __launch_bounds__(256) void proj_kernel(
    const __bf16* __restrict__ X,
    const __bf16* __restrict__ qw, const float* __restrict__ qb,
    const __bf16* __restrict__ kw, const float* __restrict__ kb,
    const __bf16* __restrict__ vw, const float* __restrict__ vb,
    __bf16* __restrict__ Qo, __bf16* __restrict__ Ko,
    __bf16* __restrict__ VTo, __bf16* __restrict__ Go)
{
  __shared__ __bf16 As[2][128][64];
  __shared__ __bf16 Bs[2][128][64];

  const int bid = blockIdx.x;
  const int r = bid >> 3;
  const int ntile = (bid & 7) * 4 + (r >> 5);
  const int mtile = r & 31;
  const int m0 = mtile * 128;
  const int n0 = ntile * 128;

  const __bf16* W; const float* bias; int nb;
  if (n0 < 2048)      { W = qw; bias = qb; nb = n0; }
  else if (n0 < 3072) { W = kw; bias = kb; nb = n0 - 2048; }
  else                { W = vw; bias = vb; nb = n0 - 3072; }

  const int tid = threadIdx.x;
  const int wv = tid >> 6, ln = tid & 63;
  const int wr = wv >> 1, wc = wv & 1;
  const int qr = ln & 15, qg = ln >> 4;
  const int lrow = ln >> 3, lcol = (ln & 7) * 8;

  f32x4 acc[4][4];
#pragma unroll
  for (int m = 0; m < 4; ++m)
#pragma unroll
    for (int n = 0; n < 4; ++n) acc[m][n] = 0.f;

  __bf16 (*Asc)[64] = As[0], (*Asn)[64] = As[1];
  __bf16 (*Bsc)[64] = Bs[0], (*Bsn)[64] = Bs[1];

  // prologue: stage k-tile 0 into current
#pragma unroll
  for (int i = 0; i < 4; ++i) {
    const int rb = i * 32 + wv * 8;
    gload16(X + (size_t)(m0 + rb + lrow) * 1024 + lcol, &Asc[rb][0]);
    gload16(W + (size_t)(nb + rb + lrow) * 1024 + lcol, &Bsc[rb][0]);
  }
  __syncthreads();

  for (int t = 0; t < 16; ++t) {
    if (t < 15) {
      const int k0 = (t + 1) * 64;
#pragma unroll
      for (int i = 0; i < 4; ++i) {
        const int rb = i * 32 + wv * 8;
        gload16(X + (size_t)(m0 + rb + lrow) * 1024 + k0 + lcol, &Asn[rb][0]);
        gload16(W + (size_t)(nb + rb + lrow) * 1024 + k0 + lcol, &Bsn[rb][0]);
      }
    }
#pragma unroll
    for (int kk = 0; kk < 2; ++kk) {
      bf16x8 af[4], bfv[4];
#pragma unroll
      for (int m = 0; m < 4; ++m) af[m] = *(const bf16x8*)&Asc[wr * 64 + m * 16 + qr][kk * 32 + qg * 8];
#pragma unroll
      for (int n = 0; n < 4; ++n) bfv[n] = *(const bf16x8*)&Bsc[wc * 64 + n * 16 + qr][kk * 32 + qg * 8];
#pragma unroll
      for (int m = 0; m < 4; ++m)
#pragma unroll
        for (int n = 0; n < 4; ++n) acc[m][n] = MFMA_BF16(af[m], bfv[n], acc[m][n]);
    }
    __syncthreads();   // drains vmcnt (next tile staged) + orders LDS reuse
    __bf16 (*ta)[64] = Asc; Asc = Asn; Asn = ta;
    __bf16 (*tb)[64] = Bsc; Bsc = Bsn; Bsn = tb;
  }

  // epilogue: C/D layout col=lane&15, row=(lane>>4)*4+reg
#pragma unroll
  for (int m = 0; m < 4; ++m) {
    const int gm0 = m0 + wr * 64 + m * 16 + qg * 4;
    const int b = gm0 >> 11;
    const int s = gm0 & 2047;
#pragma unroll
    for (int n = 0; n < 4; ++n) {
      const int nl = wc * 64 + n * 16 + qr;
      const float bb = bias[nb + nl];
      if (n0 < 1024) {            // Q -> [b,h,s,d], pre-scaled by 1/sqrt(d)
        const int col = n0 + nl, hh = col >> 6, dd = col & 63;
        __bf16* dst = Qo + ((size_t)((b << 4) + hh)) * 131072 + (size_t)s * 64 + dd;
#pragma unroll
        for (int rr = 0; rr < 4; ++rr) dst[(size_t)rr * 64] = (__bf16)((acc[m][n][rr] + bb) * 0.125f);
      } else if (n0 < 2048) {     // gate -> sigmoid -> [token, h*64+d]
        const int j = n0 - 1024 + nl;
        __bf16* dst = Go + (size_t)gm0 * 1024 + j;
#pragma unroll
        for (int rr = 0; rr < 4; ++rr) {
          const float v = acc[m][n][rr] + bb;
          dst[(size_t)rr * 1024] = (__bf16)(1.f / (1.f + __expf(-v)));
        }
      } else if (n0 < 3072) {     // K -> [b,h,s,d]
        const int j = n0 - 2048 + nl, hh = j >> 6, dd = j & 63;
        __bf16* dst = Ko + ((size_t)((b << 4) + hh)) * 131072 + (size_t)s * 64 + dd;
#pragma unroll
        for (int rr = 0; rr < 4; ++rr) dst[(size_t)rr * 64] = (__bf16)(acc[m][n][rr] + bb);
      } else {                    // V -> transposed [b,h,d,s]
        const int j = n0 - 3072 + nl, hh = j >> 6, dd = j & 63;
        bf16x4 pv;
#pragma unroll
        for (int rr = 0; rr < 4; ++rr) pv[rr] = (__bf16)(acc[m][n][rr] + bb);
        *(bf16x4*)(VTo + ((size_t)((b << 4) + hh)) * 131072 + (size_t)dd * 2048 + s) = pv;
      }
    }
  }
}

// ---------------- flash attention: dbuf LDS-staged K/V, swapped-QK^T, in-register softmax ----------------
// Block = 4 waves (256 thr) = one head, 128 q rows; wave w owns q0+w*32.
// K/V tiles (64 kv x 64 d) staged in LDS as [32 rows][256B] with 16B-granule XOR swizzle
// (b_phys = b_log ^ ((row&15)<<4)); staged via gload16 with pre-swizzled per-lane global src.
// Scores (mfma(K,Q)): lane holds S[kv=(r&3)+8(r>>2)+4hi][q=lq].
// PV (mfma(V^T,P)): lane holds O[d=32*half+(r&3)+8(r>>2)+4hi][q=lq].
__global__ __launch_bounds__(256, 2) void attn_kernel(
    const __bf16* __restrict__ Qb, const __bf16* __restrict__ Kb,
    const __bf16* __restrict__ VT, const __bf16* __restrict__ G,
    const float* __restrict__ mask, const int* __restrict__ flag,
    __bf16* __restrict__ attn)
{
  __shared__ __bf16 Ksh[2][32][128];  // 2 x 8KB, swizzled
  __shared__ __bf16 Vsh[2][32][128];

  const int bid = blockIdx.x;    // 512 = 8 xcd * (4 heads * 16 qblocks)
  const int y = bid >> 3;        // 0..63
  const int hl = (bid & 7) * 4 + (y >> 4);  // 4 heads per XCD
  const int tid = threadIdx.x;
  const int w = tid >> 6;        // wave 0..3
  const int ln = tid & 63;
  const int lq = ln & 31;
  const int hi = ln >> 5;
  const int q0 = (y & 15) * 128 + w * 32;
  const int b = hl >> 4, h = hl & 15;

  const __bf16* Qh = Qb + (size_t)hl * 131072;
  const __bf16* Kh = Kb + (size_t)hl * 131072;
  const __bf16* Vh = VT + (size_t)hl * 131072;

  // staging source offsets (elements within head), chunk-invariant parts
  int kco[2], vco[2], ldst[2];
#pragma unroll
  for (int i = 0; i < 2; ++i) {
    const int prow = w * 8 + i * 4 + (ln >> 4);  // physical LDS row 0..31
    const int bphys = (ln & 15) * 16;
    const int blog = bphys ^ ((prow & 15) << 4);
    const int half = blog >> 7;             // K: kv-half | V: d-half
    const int col = (blog & 127) >> 1;      // K: d | V: kv-local
    kco[i] = (half * 32 + prow) * 64 + col;
    vco[i] = (half * 32 + prow) * 2048 + col;
    ldst[i] = (w * 8 + i * 4) * 256;        // byte offset of instruction's LDS slab
  }
  const int swz = (lq & 15) << 4;
  const int krow = lq * 256;

  // Q as B-operand (pre-scaled by 1/8 in proj): frag ks: Q[q0+lq][16ks+8hi+0..7]
  bf16x8 qf[4];
#pragma unroll
  for (int ks = 0; ks < 4; ++ks)
    qf[ks] = *(const bf16x8*)(Qh + (size_t)(q0 + lq) * 64 + ks * 16 + hi * 8);

  f32x16 o0, o1;
#pragma unroll
  for (int i = 0; i < 16; ++i) { o0[i] = 0.f; o1[i] = 0.f; }
  float mrun = -1e30f, lrun = 0.f;

  const bool um = (*flag) != 0;

  char* Kc = (char*)&Ksh[0][0][0];  char* Kn = (char*)&Ksh[1][0][0];
  char* Vc = (char*)&Vsh[0][0][0];  char* Vn = (char*)&Vsh[1][0][0];

  // prologue: stage chunk 0
#pragma unroll
  for (int i = 0; i < 2; ++i) {
    gload16(Kh + kco[i], (__bf16*)(Kc + ldst[i]));
    gload16(Vh + vco[i], (__bf16*)(Vc + ldst[i]));
  }
  __syncthreads();

  for (int c = 0; c < 32; ++c) {
    const int kv0 = c * 64;
    if (c < 31) {
      const int kvn = kv0 + 64;
#pragma unroll
      for (int i = 0; i < 2; ++i) {
        gload16(Kh + kvn * 64 + kco[i], (__bf16*)(Kn + ldst[i]));
        gload16(Vh + kvn + vco[i],      (__bf16*)(Vn + ldst[i]));
      }
    }

#pragma unroll
    for (int s32 = 0; s32 < 2; ++s32) {
      bf16x8 kf[4];
#pragma unroll
      for (int ks = 0; ks < 4; ++ks)
        kf[ks] = *(const bf16x8*)(Kc + krow + ((s32 * 128 + ks * 32 + hi * 16) ^ swz));

      f32x16 s;
#pragma unroll
      for (int i = 0; i < 16; ++i) s[i] = 0.f;
#pragma unroll
      for (int ks = 0; ks < 4; ++ks) s = MFMA32(kf[ks], qf[ks], s);

      float p[16];
#pragma unroll
      for (int i = 0; i < 16; ++i) p[i] = s[i];

      if (um) {
        const size_t mrow = (size_t)(q0 + lq) * 2048 + kv0 + s32 * 32;
#pragma unroll
        for (int i = 0; i < 16; ++i)
          p[i] += mask[mrow + (i & 3) + 8 * (i >> 2) + 4 * hi];
      }

      // row max over 32 kv: 15 local fmax + 1 cross-half shuffle
      float t = p[0];
#pragma unroll
      for (int i = 1; i < 16; ++i) t = fmaxf(t, p[i]);
      t = fmaxf(t, __shfl_xor(t, 32));
      const float mn = fmaxf(mrun, t);
      const float alpha = __expf(mrun - mn);
      mrun = mn;

      float ps = 0.f;
#pragma unroll
      for (int i = 0; i < 16; ++i) { p[i] = __expf(p[i] - mn); ps += p[i]; }
      ps += __shfl_xor(ps, 32);
      lrun = lrun * alpha + ps;

#pragma unroll
      for (int i = 0; i < 16; ++i) { o0[i] *= alpha; o1[i] *= alpha; }

      // pack P into B-frag layout: pa[ks] holds P[q=lq][16ks + 8hi + 0..7]
      bf16x8 pa[2];
#pragma unroll
      for (int ks = 0; ks < 2; ++ks) {
        unsigned int c0 = cvtpk_bf16(p[8 * ks + 0], p[8 * ks + 1]);
        unsigned int c1 = cvtpk_bf16(p[8 * ks + 2], p[8 * ks + 3]);
        unsigned int c2 = cvtpk_bf16(p[8 * ks + 4], p[8 * ks + 5]);
        unsigned int c3 = cvtpk_bf16(p[8 * ks + 6], p[8 * ks + 7]);
        permswap(c0, c2);
        permswap(c1, c3);
        u32x4 wv; wv.x = c0; wv.y = c1; wv.z = c2; wv.w = c3;
        pa[ks] = __builtin_bit_cast(bf16x8, wv);
      }

      // PV from swizzled Vsh: V^T rows = d, cols = kv
#pragma unroll
      for (int ks = 0; ks < 2; ++ks) {
        const int kvb = s32 * 64 + ks * 32 + hi * 16;
        bf16x8 v0 = *(const bf16x8*)(Vc + krow + ((0 + kvb) ^ swz));
        bf16x8 v1 = *(const bf16x8*)(Vc + krow + ((128 + kvb) ^ swz));
        o0 = MFMA32(v0, pa[ks], o0);
        o1 = MFMA32(v1, pa[ks], o1);
      }
    }
    __syncthreads();   // drains vmcnt (next chunk staged) + orders LDS reuse
    char* tk = Kc; Kc = Kn; Kn = tk;
    char* tv = Vc; Vc = Vn; Vn = tv;
  }

  // epilogue: 1/l, gate, store. Lane: q=q0+lq fixed, d = 32*half + 8g + 4hi + j
  const float inv = 1.f / lrun;
  const size_t base = ((size_t)(b * 2048 + q0 + lq)) * 1024 + h * 64;
#pragma unroll
  for (int half = 0; half < 2; ++half) {
#pragma unroll
    for (int g = 0; g < 4; ++g) {
      const int d0 = half * 32 + g * 8 + hi * 4;
      bf16x4 g4 = *(const bf16x4*)(G + base + d0);
      bf16x4 r4;
#pragma unroll
      for (int j = 0; j < 4; ++j) {
        const float ov = half ? o1[g * 4 + j] : o0[g * 4 + j];
        r4[j] = (__bf16)(ov * inv * (float)g4[j]);
      }
      *(bf16x4*)(attn + base + d0) = r4;
    }
  }
}

// ---------------- O projection (bf16 in, fp32 out), 2-phase dbuf ----------------
__global__ __launch_bounds__(256) void oproj_kernel(
    const __bf16* __restrict__ A, const __bf16* __restrict__ ow,
    const float* __restrict__ ob, float* __restrict__ C)
{
  __shared__ __bf16 As[2][128][64];
  __shared__ __bf16 Bs[2][128][64];
  const int bid = blockIdx.x;
  const int ntile = bid & 7;
  const int mtile = bid >> 3;
  const int m0 = mtile * 128, n0 = ntile * 128;

  const int tid = threadIdx.x;
  const int wv = tid >> 6, ln = tid & 63;
  const int wr = wv >> 1, wc = wv & 1;
  const int qr = ln & 15, qg = ln >> 4;
  const int lrow = ln >> 3, lcol = (ln & 7) * 8;

  f32x4 acc[4][4];
#pragma unroll
  for (int m = 0; m < 4; ++m)
#pragma unroll
    for (int n = 0; n < 4; ++n) acc[m][n] = 0.f;

  __bf16 (*Asc)[64] = As[0], (*Asn)[64] = As[1];
  __bf16 (*Bsc)[64] = Bs[0], (*Bsn)[64] = Bs[1];

#pragma unroll
  for (int i = 0; i < 4; ++i) {
    const int rb = i * 32 + wv * 8;
    gload16(A  + (size_t)(m0 + rb + lrow) * 1024 + lcol, &Asc[rb][0]);
    gload16(ow + (size_t)(n0 + rb + lrow) * 1024 + lcol, &Bsc[rb][0]);
  }
  __syncthreads();

  for (int t = 0; t < 16; ++t) {
    if (t < 15) {
      const int k0 = (t + 1) * 64;
#pragma unroll
      for (int i = 0; i < 4; ++i) {
        const int rb = i * 32 + wv * 8;
        gload16(A  + (size_t)(m0 + rb + lrow) * 1024 + k0 + lcol, &Asn[rb][0]);
        gload16(ow + (size_t)(n0 + rb + lrow) * 1024 + k0 + lcol, &Bsn[rb][0]);
      }
    }
#pragma unroll
    for (int kk = 0; kk < 2; ++kk) {
      bf16x8 af[4], bfv[4];
#pragma unroll
      for (int m = 0; m < 4; ++m) af[m] = *(const bf16x8*)&Asc[wr * 64 + m * 16 + qr][kk * 32 + qg * 8];
#pragma unroll
      for (int n = 0; n < 4; ++n) bfv[n] = *(const bf16x8*)&Bsc[wc * 64 + n * 16 + qr][kk * 32 + qg * 8];
#pragma unroll
      for (int m = 0; m < 4; ++m)
#pragma unroll
        for (int n = 0; n < 4; ++n) acc[m][n] = MFMA_BF16(af[m], bfv[n], acc[m][n]);
    }
    __syncthreads();
    __bf16 (*ta)[64] = Asc; Asc = Asn; Asn = ta;
    __bf16 (*tb)[64] = Bsc; Bsc = Bsn; Bsn = tb;
  }

#pragma unroll
  for (int m = 0; m < 4; ++m) {
    const int gm0 = m0 + wr * 64 + m * 16 + qg * 4;
#pragma unroll
    for (int n = 0; n < 4; ++n) {
      const int gn = n0 + wc * 64 + n * 16 + qr;
      const float bb = ob[gn];
      float* dst = C + (size_t)gm0 * 1024 + gn;
#pragma unroll
      for (int rr = 0; rr < 4; ++rr) dst[(size_t)rr * 1024] = acc[m][n][rr] + bb;
    }
  }
}

extern "C" void kernel_launch(void* const* d_in, const int* in_sizes, int n_in,
                              void* d_out, int out_size, void* d_ws, size_t ws_size,
                              hipStream_t stream)
{
  const float* hs   = (const float*)d_in[0];
  const float* mask = (const float*)d_in[1];
  const float* qw   = (const float*)d_in[2];
  const float* qb   = (const float*)d_in[3];
  const float* kw   = (const float*)d_in[4];
  const float* kb   = (const float*)d_in[5];
  const float* vw   = (const float*)d_in[6];
  const float* vb   = (const float*)d_in[7];
  const float* ow   = (const float*)d_in[8];
  const float* ob   = (const float*)d_in[9];
  float* out = (float*)d_out;

  char* w = (char*)d_ws;
  int*    flag = (int*)w;
  __bf16* Xb  = (__bf16*)(w + 256);
  __bf16* qwb = Xb  + 4194304;
  __bf16* kwb = qwb + 2097152;
  __bf16* vwb = kwb + 1048576;
  __bf16* owb = vwb + 1048576;
  __bf16* Qo  = owb + 1048576;
  __bf16* Ko  = Qo  + 4194304;
  __bf16* VTo = Ko  + 4194304;
  __bf16* Go  = VTo + 4194304;
  __bf16* At  = Go  + 4194304;

  hipMemsetAsync(flag, 0, sizeof(int), stream);
  cvt_all_kernel<<<2048, 256, 0, stream>>>(hs, qw, kw, vw, ow, Xb, qwb, kwb, vwb, owb,
                                           (const unsigned long long*)mask, flag);
  proj_kernel<<<1024, 256, 0, stream>>>(Xb, qwb, qb, kwb, kb, vwb, vb, Qo, Ko, VTo, Go);
  attn_kernel<<<512, 256, 0, stream>>>(Qo, Ko, VTo, Go, mask, flag, At);
  oproj_kernel<<<256, 256, 0, stream>>>(At, owb, ob, out);
}

// Round 9
// 150.020 us; speedup vs baseline: 2.3353x; 1.0227x over previous
//
#include <hip/hip_runtime.h>
#include <cstdint>
#include <cstddef>

#define AS1 __attribute__((address_space(1)))
#define AS3 __attribute__((address_space(3)))

typedef __bf16 bf16x8 __attribute__((ext_vector_type(8)));
typedef __bf16 bf16x4 __attribute__((ext_vector_type(4)));
typedef float  f32x4  __attribute__((ext_vector_type(4)));
typedef float  f32x16 __attribute__((ext_vector_type(16)));
typedef unsigned int u32x4 __attribute__((ext_vector_type(4)));

#define MFMA_BF16(a, b, c) __builtin_amdgcn_mfma_f32_16x16x32_bf16((a), (b), (c), 0, 0, 0)
#define MFMA32(a, b, c)    __builtin_amdgcn_mfma_f32_32x32x16_bf16((a), (b), (c), 0, 0, 0)

// async global->LDS, 16B/lane. LDS base wave-uniform; HW adds lane*16. Global addr per-lane.
__device__ __forceinline__ void gload16(const __bf16* g, __bf16* l) {
  __builtin_amdgcn_global_load_lds((AS1 void*)(uintptr_t)g, (AS3 void*)l, 16, 0, 0);
}

__device__ __forceinline__ unsigned int cvtpk_bf16(float lo, float hi) {
  unsigned int r;
  asm("v_cvt_pk_bf16_f32 %0, %1, %2" : "=v"(r) : "v"(lo), "v"(hi));
  return r;
}

// v_permlane32_swap_b32 a, b : a[32:63] <-> b[0:31]
__device__ __forceinline__ void permswap(unsigned int& a, unsigned int& b) {
  asm volatile("v_permlane32_swap_b32 %0, %1" : "+v"(a), "+v"(b));
}

// raw v_exp_f32: computes 2^x
__device__ __forceinline__ float exp2_fast(float x) {
  float r;
  asm("v_exp_f32 %0, %1" : "=v"(r) : "v"(x));
  return r;
}

#define LOG2E 1.4426950408889634f

// ---------------- fp32 -> bf16 conversion (5 tensors) + mask-zero scan, one launch ----------------
__global__ void cvt_all_kernel(
    const float* __restrict__ hs, const float* __restrict__ qw, const float* __restrict__ kw,
    const float* __restrict__ vw, const float* __restrict__ ow,
    __bf16* __restrict__ Xb, __bf16* __restrict__ qwb, __bf16* __restrict__ kwb,
    __bf16* __restrict__ vwb, __bf16* __restrict__ owb,
    const unsigned long long* __restrict__ mask, int* __restrict__ flag)
{
  const int gid = blockIdx.x * blockDim.x + threadIdx.x;
  const int stride = gridDim.x * blockDim.x;
  for (int i = gid; i < 1179648; i += stride) {
    const float* s; __bf16* d; int o;
    if (i < 524288)       { s = hs; d = Xb;  o = i; }
    else if (i < 786432)  { s = qw; d = qwb; o = i - 524288; }
    else if (i < 917504)  { s = kw; d = kwb; o = i - 786432; }
    else if (i < 1048576) { s = vw; d = vwb; o = i - 917504; }
    else                  { s = ow; d = owb; o = i - 1048576; }
    const float4* p = (const float4*)(s + (size_t)o * 8);
    float4 a = p[0], b = p[1];
    bf16x8 v;
    v[0] = (__bf16)a.x; v[1] = (__bf16)a.y; v[2] = (__bf16)a.z; v[3] = (__bf16)a.w;
    v[4] = (__bf16)b.x; v[5] = (__bf16)b.y; v[6] = (__bf16)b.z; v[7] = (__bf16)b.w;
    *(bf16x8*)(d + (size_t)o * 8) = v;
  }
  bool nz = false;
  for (int i = gid; i < 2097152; i += stride) nz |= (mask[i] != 0ull);
  if (nz) atomicOr(flag, 1);
}

// ---------------- fused QGKV projection (bf16 in, bf16 out, fp32 acc), 2-phase dbuf ----------------
__global__ __launch_bounds__(256) void proj_kernel(
    const __bf16* __restrict__ X,
    const __bf16* __restrict__ qw, const float* __restrict__ qb,
    const __bf16* __restrict__ kw, const float* __restrict__ kb,
    const __bf16* __restrict__ vw, const float* __restrict__ vb,
    __bf16* __restrict__ Qo, __bf16* __restrict__ Ko,
    __bf16* __restrict__ VTo, __bf16* __restrict__ Go)
{
  __shared__ __bf16 As[2][128][64];
  __shared__ __bf16 Bs[2][128][64];

  const int bid = blockIdx.x;
  const int r = bid >> 3;
  const int ntile = (bid & 7) * 4 + (r >> 5);
  const int mtile = r & 31;
  const int m0 = mtile * 128;
  const int n0 = ntile * 128;

  const __bf16* W; const float* bias; int nb;
  if (n0 < 2048)      { W = qw; bias = qb; nb = n0; }
  else if (n0 < 3072) { W = kw; bias = kb; nb = n0 - 2048; }
  else                { W = vw; bias = vb; nb = n0 - 3072; }

  const int tid = threadIdx.x;
  const int wv = tid >> 6, ln = tid & 63;
  const int wr = wv >> 1, wc = wv & 1;
  const int qr = ln & 15, qg = ln >> 4;
  const int lrow = ln >> 3, lcol = (ln & 7) * 8;

  f32x4 acc[4][4];
#pragma unroll
  for (int m = 0; m < 4; ++m)
#pragma unroll
    for (int n = 0; n < 4; ++n) acc[m][n] = 0.f;

  __bf16 (*Asc)[64] = As[0], (*Asn)[64] = As[1];
  __bf16 (*Bsc)[64] = Bs[0], (*Bsn)[64] = Bs[1];

  // prologue: stage k-tile 0 into current
#pragma unroll
  for (int i = 0; i < 4; ++i) {
    const int rb = i * 32 + wv * 8;
    gload16(X + (size_t)(m0 + rb + lrow) * 1024 + lcol, &Asc[rb][0]);
    gload16(W + (size_t)(nb + rb + lrow) * 1024 + lcol, &Bsc[rb][0]);
  }
  __syncthreads();

  for (int t = 0; t < 16; ++t) {
    if (t < 15) {
      const int k0 = (t + 1) * 64;
#pragma unroll
      for (int i = 0; i < 4; ++i) {
        const int rb = i * 32 + wv * 8;
        gload16(X + (size_t)(m0 + rb + lrow) * 1024 + k0 + lcol, &Asn[rb][0]);
        gload16(W + (size_t)(nb + rb + lrow) * 1024 + k0 + lcol, &Bsn[rb][0]);
      }
    }
#pragma unroll
    for (int kk = 0; kk < 2; ++kk) {
      bf16x8 af[4], bfv[4];
#pragma unroll
      for (int m = 0; m < 4; ++m) af[m] = *(const bf16x8*)&Asc[wr * 64 + m * 16 + qr][kk * 32 + qg * 8];
#pragma unroll
      for (int n = 0; n < 4; ++n) bfv[n] = *(const bf16x8*)&Bsc[wc * 64 + n * 16 + qr][kk * 32 + qg * 8];
#pragma unroll
      for (int m = 0; m < 4; ++m)
#pragma unroll
        for (int n = 0; n < 4; ++n) acc[m][n] = MFMA_BF16(af[m], bfv[n], acc[m][n]);
    }
    __syncthreads();   // drains vmcnt (next tile staged) + orders LDS reuse
    __bf16 (*ta)[64] = Asc; Asc = Asn; Asn = ta;
    __bf16 (*tb)[64] = Bsc; Bsc = Bsn; Bsn = tb;
  }

  // epilogue: C/D layout col=lane&15, row=(lane>>4)*4+reg
#pragma unroll
  for (int m = 0; m < 4; ++m) {
    const int gm0 = m0 + wr * 64 + m * 16 + qg * 4;
    const int b = gm0 >> 11;
    const int s = gm0 & 2047;
#pragma unroll
    for (int n = 0; n < 4; ++n) {
      const int nl = wc * 64 + n * 16 + qr;
      const float bb = bias[nb + nl];
      if (n0 < 1024) {            // Q -> [b,h,s,d], pre-scaled by log2e/sqrt(d) (exp2-domain softmax)
        const int col = n0 + nl, hh = col >> 6, dd = col & 63;
        __bf16* dst = Qo + ((size_t)((b << 4) + hh)) * 131072 + (size_t)s * 64 + dd;
#pragma unroll
        for (int rr = 0; rr < 4; ++rr) dst[(size_t)rr * 64] = (__bf16)((acc[m][n][rr] + bb) * (0.125f * LOG2E));
      } else if (n0 < 2048) {     // gate -> sigmoid -> [token, h*64+d]
        const int j = n0 - 1024 + nl;
        __bf16* dst = Go + (size_t)gm0 * 1024 + j;
#pragma unroll
        for (int rr = 0; rr < 4; ++rr) {
          const float v = acc[m][n][rr] + bb;
          dst[(size_t)rr * 1024] = (__bf16)(1.f / (1.f + __expf(-v)));
        }
      } else if (n0 < 3072) {     // K -> [b,h,s,d]
        const int j = n0 - 2048 + nl, hh = j >> 6, dd = j & 63;
        __bf16* dst = Ko + ((size_t)((b << 4) + hh)) * 131072 + (size_t)s * 64 + dd;
#pragma unroll
        for (int rr = 0; rr < 4; ++rr) dst[(size_t)rr * 64] = (__bf16)(acc[m][n][rr] + bb);
      } else {                    // V -> transposed [b,h,d,s]
        const int j = n0 - 3072 + nl, hh = j >> 6, dd = j & 63;
        bf16x4 pv;
#pragma unroll
        for (int rr = 0; rr < 4; ++rr) pv[rr] = (__bf16)(acc[m][n][rr] + bb);
        *(bf16x4*)(VTo + ((size_t)((b << 4) + hh)) * 131072 + (size_t)dd * 2048 + s) = pv;
      }
    }
  }
}

// ---------------- flash attention: dbuf LDS-staged K/V, swapped-QK^T, exp2-domain softmax ----------------
// Block = 4 waves (256 thr) = one head, 128 q rows; wave w owns q0+w*32.
// K/V tiles (64 kv x 64 d) staged in LDS as [32 rows][256B] with 16B-granule XOR swizzle.
// Scores (mfma(K,Q)): lane holds S[kv=(r&3)+8(r>>2)+4hi][q=lq], already in log2 domain (Q pre-scaled).
// Softmax: defer-max (THR=8, per-lane), exp2, per-lane partial lrun (combined once at end).
// PV (mfma(V^T,P)): lane holds O[d=32*half+(r&3)+8(r>>2)+4hi][q=lq].
__global__ __launch_bounds__(256, 2) void attn_kernel(
    const __bf16* __restrict__ Qb, const __bf16* __restrict__ Kb,
    const __bf16* __restrict__ VT, const __bf16* __restrict__ G,
    const float* __restrict__ mask, const int* __restrict__ flag,
    __bf16* __restrict__ attn)
{
  __shared__ __bf16 Ksh[2][32][128];  // 2 x 8KB, swizzled
  __shared__ __bf16 Vsh[2][32][128];

  const int bid = blockIdx.x;    // 512 = 8 xcd * (4 heads * 16 qblocks)
  const int y = bid >> 3;        // 0..63
  const int hl = (bid & 7) * 4 + (y >> 4);  // 4 heads per XCD
  const int tid = threadIdx.x;
  const int w = tid >> 6;        // wave 0..3
  const int ln = tid & 63;
  const int lq = ln & 31;
  const int hi = ln >> 5;
  const int q0 = (y & 15) * 128 + w * 32;
  const int b = hl >> 4, h = hl & 15;

  const __bf16* Qh = Qb + (size_t)hl * 131072;
  const __bf16* Kh = Kb + (size_t)hl * 131072;
  const __bf16* Vh = VT + (size_t)hl * 131072;

  // staging source offsets (elements within head), chunk-invariant parts
  int kco[2], vco[2], ldst[2];
#pragma unroll
  for (int i = 0; i < 2; ++i) {
    const int prow = w * 8 + i * 4 + (ln >> 4);  // physical LDS row 0..31
    const int bphys = (ln & 15) * 16;
    const int blog = bphys ^ ((prow & 15) << 4);
    const int half = blog >> 7;             // K: kv-half | V: d-half
    const int col = (blog & 127) >> 1;      // K: d | V: kv-local
    kco[i] = (half * 32 + prow) * 64 + col;
    vco[i] = (half * 32 + prow) * 2048 + col;
    ldst[i] = (w * 8 + i * 4) * 256;        // byte offset of instruction's LDS slab
  }
  const int swz = (lq & 15) << 4;
  const int krow = lq * 256;

  // Q as B-operand (pre-scaled to log2 domain in proj): frag ks: Q[q0+lq][16ks+8hi+0..7]
  bf16x8 qf[4];
#pragma unroll
  for (int ks = 0; ks < 4; ++ks)
    qf[ks] = *(const bf16x8*)(Qh + (size_t)(q0 + lq) * 64 + ks * 16 + hi * 8);

  f32x16 o0, o1;
#pragma unroll
  for (int i = 0; i < 16; ++i) { o0[i] = 0.f; o1[i] = 0.f; }
  float mrun = -1e30f, lrun = 0.f;

  const bool um = (*flag) != 0;

  char* Kc = (char*)&Ksh[0][0][0];  char* Kn = (char*)&Ksh[1][0][0];
  char* Vc = (char*)&Vsh[0][0][0];  char* Vn = (char*)&Vsh[1][0][0];

  // prologue: stage chunk 0
#pragma unroll
  for (int i = 0; i < 2; ++i) {
    gload16(Kh + kco[i], (__bf16*)(Kc + ldst[i]));
    gload16(Vh + vco[i], (__bf16*)(Vc + ldst[i]));
  }
  __syncthreads();

  for (int c = 0; c < 32; ++c) {
    const int kv0 = c * 64;
    if (c < 31) {
      const int kvn = kv0 + 64;
#pragma unroll
      for (int i = 0; i < 2; ++i) {
        gload16(Kh + kvn * 64 + kco[i], (__bf16*)(Kn + ldst[i]));
        gload16(Vh + kvn + vco[i],      (__bf16*)(Vn + ldst[i]));
      }
    }

#pragma unroll
    for (int s32 = 0; s32 < 2; ++s32) {
      bf16x8 kf[4];
#pragma unroll
      for (int ks = 0; ks < 4; ++ks)
        kf[ks] = *(const bf16x8*)(Kc + krow + ((s32 * 128 + ks * 32 + hi * 16) ^ swz));

      f32x16 s;
#pragma unroll
      for (int i = 0; i < 16; ++i) s[i] = 0.f;
      __builtin_amdgcn_s_setprio(1);
#pragma unroll
      for (int ks = 0; ks < 4; ++ks) s = MFMA32(kf[ks], qf[ks], s);
      __builtin_amdgcn_s_setprio(0);

      float p[16];
      if (um) {
        const size_t mrow = (size_t)(q0 + lq) * 2048 + kv0 + s32 * 32;
#pragma unroll
        for (int i = 0; i < 16; ++i)
          p[i] = s[i] + mask[mrow + (i & 3) + 8 * (i >> 2) + 4 * hi] * LOG2E;
      } else {
#pragma unroll
        for (int i = 0; i < 16; ++i) p[i] = s[i];
      }

      // row max over 32 kv: nested-triple fmax tree + 1 cross-half shuffle
      float t = fmaxf(fmaxf(p[0], p[1]), p[2]);
      t = fmaxf(fmaxf(t, p[3]), p[4]);
      t = fmaxf(fmaxf(t, p[5]), p[6]);
      t = fmaxf(fmaxf(t, p[7]), p[8]);
      t = fmaxf(fmaxf(t, p[9]), p[10]);
      t = fmaxf(fmaxf(t, p[11]), p[12]);
      t = fmaxf(fmaxf(t, p[13]), p[14]);
      t = fmaxf(t, p[15]);
      t = fmaxf(t, __shfl_xor(t, 32));

      // defer-max: rescale only when running max grows by > 8 (rare; execz-skipped)
      if (t > mrun + 8.f) {
        const float al = exp2_fast(mrun - t);
        mrun = t;
        lrun *= al;
#pragma unroll
        for (int i = 0; i < 16; ++i) { o0[i] *= al; o1[i] *= al; }
      }

      float ps = 0.f;
#pragma unroll
      for (int i = 0; i < 16; ++i) { p[i] = exp2_fast(p[i] - mrun); ps += p[i]; }
      lrun += ps;   // per-lane partial; cross-half combine at end

      // pack P into B-frag layout: pa[ks] holds P[q=lq][16ks + 8hi + 0..7]
      bf16x8 pa[2];
#pragma unroll
      for (int ks = 0; ks < 2; ++ks) {
        unsigned int c0 = cvtpk_bf16(p[8 * ks + 0], p[8 * ks + 1]);
        unsigned int c1 = cvtpk_bf16(p[8 * ks + 2], p[8 * ks + 3]);
        unsigned int c2 = cvtpk_bf16(p[8 * ks + 4], p[8 * ks + 5]);
        unsigned int c3 = cvtpk_bf16(p[8 * ks + 6], p[8 * ks + 7]);
        permswap(c0, c2);
        permswap(c1, c3);
        u32x4 wv; wv.x = c0; wv.y = c1; wv.z = c2; wv.w = c3;
        pa[ks] = __builtin_bit_cast(bf16x8, wv);
      }

      // PV from swizzled Vsh: V^T rows = d, cols = kv
      __builtin_amdgcn_s_setprio(1);
#pragma unroll
      for (int ks = 0; ks < 2; ++ks) {
        const int kvb = s32 * 64 + ks * 32 + hi * 16;
        bf16x8 v0 = *(const bf16x8*)(Vc + krow + ((0 + kvb) ^ swz));
        bf16x8 v1 = *(const bf16x8*)(Vc + krow + ((128 + kvb) ^ swz));
        o0 = MFMA32(v0, pa[ks], o0);
        o1 = MFMA32(v1, pa[ks], o1);
      }
      __builtin_amdgcn_s_setprio(0);
    }
    __syncthreads();   // drains vmcnt (next chunk staged) + orders LDS reuse
    char* tk = Kc; Kc = Kn; Kn = tk;
    char* tv = Vc; Vc = Vn; Vn = tv;
  }

  // combine per-lane lrun across the kv-half pair, then normalize+gate+store
  lrun += __shfl_xor(lrun, 32);
  const float inv = 1.f / lrun;
  const size_t base = ((size_t)(b * 2048 + q0 + lq)) * 1024 + h * 64;
#pragma unroll
  for (int half = 0; half < 2; ++half) {
#pragma unroll
    for (int g = 0; g < 4; ++g) {
      const int d0 = half * 32 + g * 8 + hi * 4;
      bf16x4 g4 = *(const bf16x4*)(G + base + d0);
      bf16x4 r4;
#pragma unroll
      for (int j = 0; j < 4; ++j) {
        const float ov = half ? o1[g * 4 + j] : o0[g * 4 + j];
        r4[j] = (__bf16)(ov * inv * (float)g4[j]);
      }
      *(bf16x4*)(attn + base + d0) = r4;
    }
  }
}

// ---------------- O projection (bf16 in, fp32 out), 2-phase dbuf ----------------
__global__ __launch_bounds__(256) void oproj_kernel(
    const __bf16* __restrict__ A, const __bf16* __restrict__ ow,
    const float* __restrict__ ob, float* __restrict__ C)
{
  __shared__ __bf16 As[2][128][64];
  __shared__ __bf16 Bs[2][128][64];
  const int bid = blockIdx.x;
  const int ntile = bid & 7;
  const int mtile = bid >> 3;
  const int m0 = mtile * 128, n0 = ntile * 128;

  const int tid = threadIdx.x;
  const int wv = tid >> 6, ln = tid & 63;
  const int wr = wv >> 1, wc = wv & 1;
  const int qr = ln & 15, qg = ln >> 4;
  const int lrow = ln >> 3, lcol = (ln & 7) * 8;

  f32x4 acc[4][4];
#pragma unroll
  for (int m = 0; m < 4; ++m)
#pragma unroll
    for (int n = 0; n < 4; ++n) acc[m][n] = 0.f;

  __bf16 (*Asc)[64] = As[0], (*Asn)[64] = As[1];
  __bf16 (*Bsc)[64] = Bs[0], (*Bsn)[64] = Bs[1];

#pragma unroll
  for (int i = 0; i < 4; ++i) {
    const int rb = i * 32 + wv * 8;
    gload16(A  + (size_t)(m0 + rb + lrow) * 1024 + lcol, &Asc[rb][0]);
    gload16(ow + (size_t)(n0 + rb + lrow) * 1024 + lcol, &Bsc[rb][0]);
  }
  __syncthreads();

  for (int t = 0; t < 16; ++t) {
    if (t < 15) {
      const int k0 = (t + 1) * 64;
#pragma unroll
      for (int i = 0; i < 4; ++i) {
        const int rb = i * 32 + wv * 8;
        gload16(A  + (size_t)(m0 + rb + lrow) * 1024 + k0 + lcol, &Asn[rb][0]);
        gload16(ow + (size_t)(n0 + rb + lrow) * 1024 + k0 + lcol, &Bsn[rb][0]);
      }
    }
#pragma unroll
    for (int kk = 0; kk < 2; ++kk) {
      bf16x8 af[4], bfv[4];
#pragma unroll
      for (int m = 0; m < 4; ++m) af[m] = *(const bf16x8*)&Asc[wr * 64 + m * 16 + qr][kk * 32 + qg * 8];
#pragma unroll
      for (int n = 0; n < 4; ++n) bfv[n] = *(const bf16x8*)&Bsc[wc * 64 + n * 16 + qr][kk * 32 + qg * 8];
#pragma unroll
      for (int m = 0; m < 4; ++m)
#pragma unroll
        for (int n = 0; n < 4; ++n) acc[m][n] = MFMA_BF16(af[m], bfv[n], acc[m][n]);
    }
    __syncthreads();
    __bf16 (*ta)[64] = Asc; Asc = Asn; Asn = ta;
    __bf16 (*tb)[64] = Bsc; Bsc = Bsn; Bsn = tb;
  }

#pragma unroll
  for (int m = 0; m < 4; ++m) {
    const int gm0 = m0 + wr * 64 + m * 16 + qg * 4;
#pragma unroll
    for (int n = 0; n < 4; ++n) {
      const int gn = n0 + wc * 64 + n * 16 + qr;
      const float bb = ob[gn];
      float* dst = C + (size_t)gm0 * 1024 + gn;
#pragma unroll
      for (int rr = 0; rr < 4; ++rr) dst[(size_t)rr * 1024] = acc[m][n][rr] + bb;
    }
  }
}

extern "C" void kernel_launch(void* const* d_in, const int* in_sizes, int n_in,
                              void* d_out, int out_size, void* d_ws, size_t ws_size,
                              hipStream_t stream)
{
  const float* hs   = (const float*)d_in[0];
  const float* mask = (const float*)d_in[1];
  const float* qw   = (const float*)d_in[2];
  const float* qb   = (const float*)d_in[3];
  const float* kw   = (const float*)d_in[4];
  const float* kb   = (const float*)d_in[5];
  const float* vw   = (const float*)d_in[6];
  const float* vb   = (const float*)d_in[7];
  const float* ow   = (const float*)d_in[8];
  const float* ob   = (const float*)d_in[9];
  float* out = (float*)d_out;

  char* w = (char*)d_ws;
  int*    flag = (int*)w;
  __bf16* Xb  = (__bf16*)(w + 256);
  __bf16* qwb = Xb  + 4194304;
  __bf16* kwb = qwb + 2097152;
  __bf16* vwb = kwb + 1048576;
  __bf16* owb = vwb + 1048576;
  __bf16* Qo  = owb + 1048576;
  __bf16* Ko  = Qo  + 4194304;
  __bf16* VTo = Ko  + 4194304;
  __bf16* Go  = VTo + 4194304;
  __bf16* At  = Go  + 4194304;

  hipMemsetAsync(flag, 0, sizeof(int), stream);
  cvt_all_kernel<<<2048, 256, 0, stream>>>(hs, qw, kw, vw, ow, Xb, qwb, kwb, vwb, owb,
                                           (const unsigned long long*)mask, flag);
  proj_kernel<<<1024, 256, 0, stream>>>(Xb, qwb, qb, kwb, kb, vwb, vb, Qo, Ko, VTo, Go);
  attn_kernel<<<512, 256, 0, stream>>>(Qo, Ko, VTo, Go, mask, flag, At);
  oproj_kernel<<<256, 256, 0, stream>>>(At, owb, ob, out);
}